// Round 8
// baseline (485.413 us; speedup 1.0000x reference)
//
#include <hip/hip_runtime.h>
#include <stdint.h>
#include <stddef.h>

typedef __bf16 bf16_t;
typedef __bf16 bf16x8 __attribute__((ext_vector_type(8)));
typedef __bf16 bf16x4 __attribute__((ext_vector_type(4)));
typedef __bf16 bf16x2 __attribute__((ext_vector_type(2)));
typedef float  f32x4  __attribute__((ext_vector_type(4)));
typedef float  f32x16 __attribute__((ext_vector_type(16)));

#define SEQ   3072
#define DIMD  2048
#define NH    16
#define HD    128
#define QKVN  6144

__device__ __forceinline__ void async16(const bf16_t* g, bf16_t* l) {
  __builtin_amdgcn_global_load_lds((const __attribute__((address_space(1))) uint32_t*)g,
                                   (__attribute__((address_space(3))) uint32_t*)l, 16, 0, 0);
}

// ---------------- fused converts + bias pack (one launch) ----------------
__global__ __launch_bounds__(256) void cvt_all(const float* __restrict__ x,
                                               const float* __restrict__ Wq,
                                               const float* __restrict__ Wk,
                                               const float* __restrict__ Wv,
                                               const float* __restrict__ Wo,
                                               const float* __restrict__ bq,
                                               const float* __restrict__ bk,
                                               const float* __restrict__ bv,
                                               bf16_t* __restrict__ xb,
                                               bf16_t* __restrict__ Wqkvb,
                                               bf16_t* __restrict__ Wob,
                                               float* __restrict__ bqkv) {
  const int b = blockIdx.x;
  const float* src; bf16_t* dst; int off;
  if (b < 3072)       { src = x;  dst = xb;              off = b; }
  else if (b < 5120)  { src = Wq; dst = Wqkvb;           off = b - 3072; }
  else if (b < 7168)  { src = Wk; dst = Wqkvb + 4194304; off = b - 5120; }
  else if (b < 9216)  { src = Wv; dst = Wqkvb + 8388608; off = b - 7168; }
  else if (b < 11264) { src = Wo; dst = Wob;             off = b - 9216; }
  else {  // bias pack: 24 blocks cover 6144
    int t = (b - 11264) * 256 + threadIdx.x;
    float v;
    if (t < 2048)      v = bq[t];
    else if (t < 4096) v = bk[t - 2048];
    else               v = bv[t - 4096];
    bqkv[t] = v;
    return;
  }
  const int idx = (off * 256 + threadIdx.x) * 8;
  const float4 a = *(const float4*)(src + idx);
  const float4 c = *(const float4*)(src + idx + 4);
  bf16x8 o;
  o[0] = (bf16_t)a.x; o[1] = (bf16_t)a.y; o[2] = (bf16_t)a.z; o[3] = (bf16_t)a.w;
  o[4] = (bf16_t)c.x; o[5] = (bf16_t)c.y; o[6] = (bf16_t)c.z; o[7] = (bf16_t)c.w;
  *(bf16x8*)(dst + idx) = o;
}

// ---------------- GEMM: C[M,N] = A[M,K] * B[N,K]^T + bias (128^2 tile) ----------------
template<bool OUT_BF16>
__global__ __launch_bounds__(256, 3) void gemm_nt(const bf16_t* __restrict__ A,
                                                  const bf16_t* __restrict__ B,
                                                  const float* __restrict__ bias,
                                                  void* __restrict__ Cout,
                                                  int M, int N, int K) {
  __shared__ __align__(16) bf16_t As[128 * 64];
  __shared__ __align__(16) bf16_t Bs[128 * 64];
  const int t = threadIdx.x;
  const int lane = t & 63, wave = t >> 6;
  const int quad = lane >> 4, l15 = lane & 15;
  const int wy = wave >> 1, wx = wave & 1;
  const size_t bm = (size_t)blockIdx.y * 128, bn = (size_t)blockIdx.x * 128;
  const bf16_t* Ab = A + bm * K;
  const bf16_t* Bb = B + bn * K;
  f32x4 acc[4][4] = {};
  int srow[4], scol[4];
#pragma unroll
  for (int r = 0; r < 4; r++) {
    int L = r * 256 + t;
    int row = L >> 3, cp = L & 7;
    srow[r] = row;
    scol[r] = (cp ^ (row & 7)) * 8;
  }
  for (int k0 = 0; k0 < K; k0 += 64) {
    __syncthreads();
#pragma unroll
    for (int r = 0; r < 4; r++)
      async16(Ab + (size_t)srow[r] * K + k0 + scol[r], &As[(r * 256 + t) * 8]);
#pragma unroll
    for (int r = 0; r < 4; r++)
      async16(Bb + (size_t)srow[r] * K + k0 + scol[r], &Bs[(r * 256 + t) * 8]);
    __syncthreads();
#pragma unroll
    for (int ks = 0; ks < 2; ks++) {
      bf16x8 af[4], bfv[4];
#pragma unroll
      for (int i = 0; i < 4; i++) {
        int row = wy * 64 + i * 16 + l15;
        af[i] = *(const bf16x8*)&As[row * 64 + (((ks * 4 + quad) ^ (row & 7)) * 8)];
      }
#pragma unroll
      for (int j = 0; j < 4; j++) {
        int row = wx * 64 + j * 16 + l15;
        bfv[j] = *(const bf16x8*)&Bs[row * 64 + (((ks * 4 + quad) ^ (row & 7)) * 8)];
      }
#pragma unroll
      for (int i = 0; i < 4; i++)
#pragma unroll
        for (int j = 0; j < 4; j++)
          acc[i][j] = __builtin_amdgcn_mfma_f32_16x16x32_bf16(af[i], bfv[j], acc[i][j], 0, 0, 0);
    }
  }
#pragma unroll
  for (int i = 0; i < 4; i++) {
#pragma unroll
    for (int j = 0; j < 4; j++) {
      size_t row = bm + wy * 64 + i * 16 + quad * 4;
      size_t col = bn + wx * 64 + j * 16 + l15;
      float bb = bias[col];
#pragma unroll
      for (int r = 0; r < 4; r++) {
        float v = acc[i][j][r] + bb;
        if (OUT_BF16) ((bf16_t*)Cout)[(row + r) * N + col] = (bf16_t)v;
        else          ((float*)Cout)[(row + r) * N + col] = v;
      }
    }
  }
}

// ---------------- RMS + RoPE; q in-place, k packed to pk[h][s][d] ----------------
// NOTE: q is additionally scaled by (1/sqrt(128))*log2(e) = 0.12751745 so that
// flash_attn can use exp2 directly with NO per-element scale multiply.
__global__ __launch_bounds__(256) void rmsrope(bf16_t* __restrict__ qkv,
                                               bf16_t* __restrict__ pk,
                                               const float* __restrict__ gq,
                                               const float* __restrict__ gk,
                                               const float* __restrict__ freqs) {
  const int s = blockIdx.x, t = threadIdx.x;
  bf16_t* row = qkv + (size_t)s * QKVN;
  bf16x8 qv = *(const bf16x8*)&row[t * 8];
  bf16x8 kv = *(const bf16x8*)&row[2048 + t * 8];
  float qf[8], kf[8];
  float qs = 0.f, ks2 = 0.f;
#pragma unroll
  for (int i = 0; i < 8; i++) {
    qf[i] = (float)qv[i]; qs  += qf[i] * qf[i];
    kf[i] = (float)kv[i]; ks2 += kf[i] * kf[i];
  }
#pragma unroll
  for (int m = 1; m < 64; m <<= 1) {
    qs  += __shfl_xor(qs, m);
    ks2 += __shfl_xor(ks2, m);
  }
  __shared__ float red[2][4];
  const int wave = t >> 6, lane = t & 63;
  if (lane == 0) { red[0][wave] = qs; red[1][wave] = ks2; }
  __syncthreads();
  qs  = red[0][0] + red[0][1] + red[0][2] + red[0][3];
  ks2 = red[1][0] + red[1][1] + red[1][2] + red[1][3];
  const float qsc = rsqrtf(qs  / 2048.f + 1e-6f) * 0.12751745f; // fold attn scale*log2e
  const float ksc = rsqrtf(ks2 / 2048.f + 1e-6f);
  const int sf = s / 384, rem = s - sf * 384;
  const int sh = rem / 24, sw = rem - sh * 24;
  bf16x8 qo, ko;
#pragma unroll
  for (int u = 0; u < 4; u++) {
    const int col = t * 8 + 2 * u;
    const int i = (col >> 1) & 63;                         // pair index within head (c=64)
    const int frow = (i < 22) ? sf : ((i < 43) ? sh : sw); // cf=22, ch=cw=21
    const float ang = freqs[frow * 64 + i];
    float sn, cs;
    __sincosf(ang, &sn, &cs);
    float te = qf[2 * u]     * qsc * gq[col];
    float to = qf[2 * u + 1] * qsc * gq[col + 1];
    qo[2 * u]     = (bf16_t)(te * cs - to * sn);
    qo[2 * u + 1] = (bf16_t)(te * sn + to * cs);
    te = kf[2 * u]     * ksc * gk[col];
    to = kf[2 * u + 1] * ksc * gk[col + 1];
    ko[2 * u]     = (bf16_t)(te * cs - to * sn);
    ko[2 * u + 1] = (bf16_t)(te * sn + to * cs);
  }
  *(bf16x8*)&row[t * 8] = qo;
  // packed K: pk[h][s][d], h = t>>4, d = (t&15)*8
  *(bf16x8*)&pk[((size_t)(t >> 4) * SEQ + s) * HD + (t & 15) * 8] = ko;
}

// ---------------- V repack: fragment-major pvtf[h][kt][(c*4+dj)*32+l31] ----------------
// Each 16B fragment = V^T[d = dj*32+l31][kv local chunk c], i.e. 8 consecutive kv at
// fixed d — exactly the PV-step MFMA B-fragment. flash reads these with lane-contiguous
// (coalesced) 1KB/wave global loads from L2, removing V from LDS entirely.
__global__ __launch_bounds__(256) void vtrans(const bf16_t* __restrict__ qkv,
                                              bf16_t* __restrict__ pvtf) {
  __shared__ bf16_t tile[128][65];
  const int h = blockIdx.y;
  const int kt = blockIdx.x;        // one 64-kv flash tile per block
  const int s0 = kt * 64;
  const int t = threadIdx.x;
#pragma unroll
  for (int r = 0; r < 4; r++) {
    int L = r * 256 + t, s = L >> 4, cp = L & 15;
    bf16x8 v = *(const bf16x8*)&qkv[(size_t)(s0 + s) * QKVN + 4096 + h * HD + cp * 8];
#pragma unroll
    for (int i = 0; i < 8; i++) tile[cp * 8 + i][s] = v[i];
  }
  __syncthreads();
#pragma unroll
  for (int r = 0; r < 4; r++) {
    int L = r * 256 + t, c = L >> 7, d = L & 127;   // c: kv-chunk 0..7, d: 0..127
    bf16x8 o;
#pragma unroll
    for (int i = 0; i < 8; i++) o[i] = tile[d][c * 8 + i];
    *(bf16x8*)&pvtf[((size_t)h * 48 + kt) * 8192 + (size_t)(((c * 4 + (d >> 5)) * 32 + (d & 31)) * 8)] = o;
  }
}

// ---------------- Flash attention v7: V direct from L2 (fragment-major), K in LDS ----------------
// Grid 512 x 192thr (3 waves x 32 q rows). XCD head-clustering swizzle: wg=(f&7)*64+f>>3
// puts 2 heads per XCD -> K+V (3MB) L2-resident; V fragments read straight to VGPRs
// (no Vt LDS, no V staging): LDS reads/wave-tile 32->16, LDS 64KB->32KB.
#define STAGE_K(BUF, KV1) do {                                               \
    _Pragma("unroll")                                                        \
    for (int r = 0; r < 5; r++) {                                            \
      int L = r * 192 + t;                                                   \
      async16(pkh + (size_t)(KV1) * HD + koff[r], &Ks[BUF][L * 8]);          \
    }                                                                        \
    if (t < 64) {                                                            \
      int L = 960 + t;                                                       \
      async16(pkh + (size_t)(KV1) * HD + koff[5], &Ks[BUF][L * 8]);          \
    }                                                                        \
  } while (0)

__global__ __launch_bounds__(192, 2) void flash_attn(const bf16_t* __restrict__ qkv,
                                                     const bf16_t* __restrict__ pk,
                                                     const bf16_t* __restrict__ pvtf,
                                                     bf16_t* __restrict__ ob) {
  __shared__ __align__(16) bf16_t Ks[2][64 * 128];  // [kv][d], 16 chunks/row, xor-swizzled
  const int f = blockIdx.x;
  const int wg = (f & 7) * 64 + (f >> 3);           // XCD x owns wg in [x*64, x*64+63] = 2 heads
  const int hh = wg >> 5, qt = wg & 31;
  const int s0 = qt * 96;
  const int t = threadIdx.x, wave = t >> 6, lane = t & 63;
  const int l31 = lane & 31, hl = lane >> 5;
  const int wq = wave * 32;
  const bf16_t* pkh = pk + (size_t)hh * (SEQ * HD);
  int koff[6];
#pragma unroll
  for (int r = 0; r < 6; r++) {
    int L = r * 192 + t;
    int krow = L >> 4, kc = (L & 15) ^ (krow & 7);
    koff[r] = krow * HD + kc * 8;
  }
  // Q fragments (B-operand): lane holds Q[q=l31][d = ks*16 + hl*8 + j]
  bf16x8 qfr[8];
#pragma unroll
  for (int ks = 0; ks < 8; ks++)
    qfr[ks] = *(const bf16x8*)&qkv[(size_t)(s0 + wq + l31) * QKVN + hh * HD + ks * 16 + hl * 8];
  bf16x8 vones;
#pragma unroll
  for (int i = 0; i < 8; i++) vones[i] = (bf16_t)1.0f;
  f32x16 oacc[4] = {};  // O[q(per-reg)][d = dj*32 + l31]
  f32x16 lacc = {};     // row-sum of P, same q-per-reg layout
  STAGE_K(0, 0);
  for (int kt = 0; kt < SEQ / 64; kt++) {
    const int cur = kt & 1;
    __syncthreads();  // K tile kt landed; all waves done reading buf cur^1
    if (kt + 1 < SEQ / 64) STAGE_K(cur ^ 1, (kt + 1) * 64);
    // V fragments for this tile: 16 coalesced 1KB/wave global loads (L2-resident),
    // issued BEFORE the QK chain so L2 latency hides under the MFMAs.
    const bf16_t* vfb = pvtf + ((size_t)hh * 48 + kt) * 8192;
    bf16x8 vf[4][4];
#pragma unroll
    for (int S = 0; S < 4; S++)
#pragma unroll
      for (int dj = 0; dj < 4; dj++)
        vf[S][dj] = *(const bf16x8*)&vfb[(size_t)((((S * 2 + hl) * 4 + dj) * 32 + l31) * 8)];
    // S^T = K * Q^T: st0 = kv 0..31, st1 = kv 32..63; col = q = l31,
    // row(reg r) = (r&3) + 8*(r>>2) + 4*hl. Log2 domain (Q pre-scaled).
    f32x16 st0 = {}, st1 = {};
    __builtin_amdgcn_s_setprio(1);
#pragma unroll
    for (int ks = 0; ks < 8; ks++) {
      const int r1 = 32 + l31;
      bf16x8 k0 = *(const bf16x8*)&Ks[cur][l31 * 128 + (((ks * 2 + hl) ^ (l31 & 7)) * 8)];
      bf16x8 k1 = *(const bf16x8*)&Ks[cur][r1 * 128 + (((ks * 2 + hl) ^ (r1 & 7)) * 8)];
      st0 = __builtin_amdgcn_mfma_f32_32x32x16_bf16(k0, qfr[ks], st0, 0, 0, 0);
      st1 = __builtin_amdgcn_mfma_f32_32x32x16_bf16(k1, qfr[ks], st1, 0, 0, 0);
    }
    __builtin_amdgcn_s_setprio(0);
    // P = exp2(st), fixed m=0 (|st| <~ 8 in log2 domain; validated R3/R4/R6 absmax)
    uint32_t c0[8], c1[8];
#pragma unroll
    for (int m = 0; m < 8; m++) {
      bf16x2 w0, w1;
      w0[0] = (bf16_t)__builtin_amdgcn_exp2f(st0[2 * m]);
      w0[1] = (bf16_t)__builtin_amdgcn_exp2f(st0[2 * m + 1]);
      w1[0] = (bf16_t)__builtin_amdgcn_exp2f(st1[2 * m]);
      w1[1] = (bf16_t)__builtin_amdgcn_exp2f(st1[2 * m + 1]);
      c0[m] = __builtin_bit_cast(uint32_t, w0);
      c1[m] = __builtin_bit_cast(uint32_t, w1);
    }
    // Build PV A-fragments: afrS holds P[q=l31][kv = S*16 + hl*8 + j].
    union U8 { uint32_t u[4]; bf16x8 v; } afr0, afr1, afr2, afr3;
#define BUILD_AFR(DST, CB, B) do {                                           \
      uint32_t sA = hl ? CB[(B) + 0] : CB[(B) + 2];                          \
      uint32_t sB = hl ? CB[(B) + 1] : CB[(B) + 3];                          \
      uint32_t rA = (uint32_t)__shfl_xor((int)sA, 32);                       \
      uint32_t rB = (uint32_t)__shfl_xor((int)sB, 32);                       \
      DST.u[0] = hl ? rA : CB[(B) + 0];                                      \
      DST.u[1] = hl ? rB : CB[(B) + 1];                                      \
      DST.u[2] = hl ? CB[(B) + 2] : rA;                                      \
      DST.u[3] = hl ? CB[(B) + 3] : rB;                                      \
    } while (0)
    BUILD_AFR(afr0, c0, 0);
    BUILD_AFR(afr1, c0, 4);
    BUILD_AFR(afr2, c1, 0);
    BUILD_AFR(afr3, c1, 4);
#undef BUILD_AFR
    // O += P * V ; l += P * 1 (ones-column trick)
    __builtin_amdgcn_s_setprio(1);
#define PV_STEP(AFR, S) do {                                                            \
      lacc = __builtin_amdgcn_mfma_f32_32x32x16_bf16(AFR.v, vones, lacc, 0, 0, 0);      \
      _Pragma("unroll")                                                                 \
      for (int dj = 0; dj < 4; dj++)                                                    \
        oacc[dj] = __builtin_amdgcn_mfma_f32_32x32x16_bf16(AFR.v, vf[S][dj], oacc[dj], 0, 0, 0); \
    } while (0)
    PV_STEP(afr0, 0);
    PV_STEP(afr1, 1);
    PV_STEP(afr2, 2);
    PV_STEP(afr3, 3);
#undef PV_STEP
    __builtin_amdgcn_s_setprio(0);
  }
  // epilogue: divide by l (rows aligned with oacc), store bf16 into ob [s][n*d]
#pragma unroll
  for (int r = 0; r < 16; r++) {
    const float li = 1.f / lacc[r];
    const size_t row = (size_t)(s0 + wq + (r & 3) + 8 * (r >> 2) + 4 * hl);
#pragma unroll
    for (int dj = 0; dj < 4; dj++)
      ob[row * DIMD + hh * HD + dj * 32 + l31] = (bf16_t)(oacc[dj][r] * li);
  }
}

// ---------------- launch ----------------
extern "C" void kernel_launch(void* const* d_in, const int* in_sizes, int n_in,
                              void* d_out, int out_size, void* d_ws, size_t ws_size,
                              hipStream_t stream) {
  (void)in_sizes; (void)n_in; (void)out_size;
  const float* x     = (const float*)d_in[0];
  const float* freqs = (const float*)d_in[1];
  const float* Wq    = (const float*)d_in[2];
  const float* bq    = (const float*)d_in[3];
  const float* Wk    = (const float*)d_in[4];
  const float* bk    = (const float*)d_in[5];
  const float* Wv    = (const float*)d_in[6];
  const float* bv    = (const float*)d_in[7];
  const float* Wo    = (const float*)d_in[8];
  const float* bo    = (const float*)d_in[9];
  const float* gq    = (const float*)d_in[10];
  const float* gk    = (const float*)d_in[11];

  // workspace carve (bytes); [0, 37748736) holds xb+Wqkvb during gemm1,
  // reused afterwards for pk / pvtf.
  char* w = (char*)d_ws;
  bf16_t* xb    = (bf16_t*)(w);                 // x bf16:        12,582,912 B
  bf16_t* Wqkvb = (bf16_t*)(w + 12582912);      // Wq|Wk|Wv bf16: 25,165,824 B
  bf16_t* Wob   = (bf16_t*)(w + 37748736);      // Wo bf16:        8,388,608 B
  bf16_t* qkvb  = (bf16_t*)(w + 46137344);      // qkv bf16:      37,748,736 B
  bf16_t* obuf  = (bf16_t*)(w + 83886080);      // attn out bf16: 12,582,912 B
  float*  bqkv  = (float*) (w + 96468992);      // stacked bias:      24,576 B
  bf16_t* pk    = (bf16_t*)(w);                 // K packed [16][3072][128]: 12,582,912 B
  bf16_t* pvtf  = (bf16_t*)(w + 12582912);      // V fragment-major [16][48][8192]: 12,582,912 B
  if (ws_size < (size_t)96493568) return;

  // converts + bias pack (one launch)
  cvt_all<<<11288, 256, 0, stream>>>(x, Wq, Wk, Wv, Wo, bq, bk, bv, xb, Wqkvb, Wob, bqkv);

  // qkv = x @ [Wq;Wk;Wv]^T + bias   (3072 x 6144 x 2048)
  gemm_nt<true><<<dim3(48, 24), 256, 0, stream>>>(xb, Wqkvb, bqkv, qkvb, SEQ, QKVN, DIMD);
  // RMS(q,k) * g + grid RoPE; q in-place (pre-scaled by scale*log2e), k -> pk
  rmsrope<<<3072, 256, 0, stream>>>(qkvb, pk, gq, gk, freqs);
  // V repack -> fragment-major pvtf
  vtrans<<<dim3(48, NH), 256, 0, stream>>>(qkvb, pvtf);
  // attention (V from L2, K in LDS, XCD head-clustering) -> obuf
  flash_attn<<<dim3(512), 192, 0, stream>>>(qkvb, pk, pvtf, obuf);
  // out = obuf @ Wo^T + bo  (3072 x 2048 x 2048), fp32 out
  gemm_nt<false><<<dim3(16, 24), 256, 0, stream>>>(obuf, Wob, bo, (float*)d_out, SEQ, DIMD, DIMD);
}

// Round 9
// 484.800 us; speedup vs baseline: 1.0013x; 1.0013x over previous
//
#include <hip/hip_runtime.h>
#include <stdint.h>
#include <stddef.h>

typedef __bf16 bf16_t;
typedef __bf16 bf16x8 __attribute__((ext_vector_type(8)));
typedef __bf16 bf16x4 __attribute__((ext_vector_type(4)));
typedef __bf16 bf16x2 __attribute__((ext_vector_type(2)));
typedef float  f32x4  __attribute__((ext_vector_type(4)));
typedef float  f32x16 __attribute__((ext_vector_type(16)));

#define SEQ   3072
#define DIMD  2048
#define NH    16
#define HD    128
#define QKVN  6144

__device__ __forceinline__ void async16(const bf16_t* g, bf16_t* l) {
  __builtin_amdgcn_global_load_lds((const __attribute__((address_space(1))) uint32_t*)g,
                                   (__attribute__((address_space(3))) uint32_t*)l, 16, 0, 0);
}

// ---------------- fused converts + bias pack (one launch) ----------------
__global__ __launch_bounds__(256) void cvt_all(const float* __restrict__ x,
                                               const float* __restrict__ Wq,
                                               const float* __restrict__ Wk,
                                               const float* __restrict__ Wv,
                                               const float* __restrict__ Wo,
                                               const float* __restrict__ bq,
                                               const float* __restrict__ bk,
                                               const float* __restrict__ bv,
                                               bf16_t* __restrict__ xb,
                                               bf16_t* __restrict__ Wqkvb,
                                               bf16_t* __restrict__ Wob,
                                               float* __restrict__ bqkv) {
  const int b = blockIdx.x;
  const float* src; bf16_t* dst; int off;
  if (b < 3072)       { src = x;  dst = xb;              off = b; }
  else if (b < 5120)  { src = Wq; dst = Wqkvb;           off = b - 3072; }
  else if (b < 7168)  { src = Wk; dst = Wqkvb + 4194304; off = b - 5120; }
  else if (b < 9216)  { src = Wv; dst = Wqkvb + 8388608; off = b - 7168; }
  else if (b < 11264) { src = Wo; dst = Wob;             off = b - 9216; }
  else {  // bias pack: 24 blocks cover 6144
    int t = (b - 11264) * 256 + threadIdx.x;
    float v;
    if (t < 2048)      v = bq[t];
    else if (t < 4096) v = bk[t - 2048];
    else               v = bv[t - 4096];
    bqkv[t] = v;
    return;
  }
  const int idx = (off * 256 + threadIdx.x) * 8;
  const float4 a = *(const float4*)(src + idx);
  const float4 c = *(const float4*)(src + idx + 4);
  bf16x8 o;
  o[0] = (bf16_t)a.x; o[1] = (bf16_t)a.y; o[2] = (bf16_t)a.z; o[3] = (bf16_t)a.w;
  o[4] = (bf16_t)c.x; o[5] = (bf16_t)c.y; o[6] = (bf16_t)c.z; o[7] = (bf16_t)c.w;
  *(bf16x8*)(dst + idx) = o;
}

// ---------------- GEMM: C[M,N] = A[M,K] * B[N,K]^T + bias (128^2 tile) ----------------
template<bool OUT_BF16>
__global__ __launch_bounds__(256, 3) void gemm_nt(const bf16_t* __restrict__ A,
                                                  const bf16_t* __restrict__ B,
                                                  const float* __restrict__ bias,
                                                  void* __restrict__ Cout,
                                                  int M, int N, int K) {
  __shared__ __align__(16) bf16_t As[128 * 64];
  __shared__ __align__(16) bf16_t Bs[128 * 64];
  const int t = threadIdx.x;
  const int lane = t & 63, wave = t >> 6;
  const int quad = lane >> 4, l15 = lane & 15;
  const int wy = wave >> 1, wx = wave & 1;
  const size_t bm = (size_t)blockIdx.y * 128, bn = (size_t)blockIdx.x * 128;
  const bf16_t* Ab = A + bm * K;
  const bf16_t* Bb = B + bn * K;
  f32x4 acc[4][4] = {};
  int srow[4], scol[4];
#pragma unroll
  for (int r = 0; r < 4; r++) {
    int L = r * 256 + t;
    int row = L >> 3, cp = L & 7;
    srow[r] = row;
    scol[r] = (cp ^ (row & 7)) * 8;
  }
  for (int k0 = 0; k0 < K; k0 += 64) {
    __syncthreads();
#pragma unroll
    for (int r = 0; r < 4; r++)
      async16(Ab + (size_t)srow[r] * K + k0 + scol[r], &As[(r * 256 + t) * 8]);
#pragma unroll
    for (int r = 0; r < 4; r++)
      async16(Bb + (size_t)srow[r] * K + k0 + scol[r], &Bs[(r * 256 + t) * 8]);
    __syncthreads();
#pragma unroll
    for (int ks = 0; ks < 2; ks++) {
      bf16x8 af[4], bfv[4];
#pragma unroll
      for (int i = 0; i < 4; i++) {
        int row = wy * 64 + i * 16 + l15;
        af[i] = *(const bf16x8*)&As[row * 64 + (((ks * 4 + quad) ^ (row & 7)) * 8)];
      }
#pragma unroll
      for (int j = 0; j < 4; j++) {
        int row = wx * 64 + j * 16 + l15;
        bfv[j] = *(const bf16x8*)&Bs[row * 64 + (((ks * 4 + quad) ^ (row & 7)) * 8)];
      }
#pragma unroll
      for (int i = 0; i < 4; i++)
#pragma unroll
        for (int j = 0; j < 4; j++)
          acc[i][j] = __builtin_amdgcn_mfma_f32_16x16x32_bf16(af[i], bfv[j], acc[i][j], 0, 0, 0);
    }
  }
#pragma unroll
  for (int i = 0; i < 4; i++) {
#pragma unroll
    for (int j = 0; j < 4; j++) {
      size_t row = bm + wy * 64 + i * 16 + quad * 4;
      size_t col = bn + wx * 64 + j * 16 + l15;
      float bb = bias[col];
#pragma unroll
      for (int r = 0; r < 4; r++) {
        float v = acc[i][j][r] + bb;
        if (OUT_BF16) ((bf16_t*)Cout)[(row + r) * N + col] = (bf16_t)v;
        else          ((float*)Cout)[(row + r) * N + col] = v;
      }
    }
  }
}

// ---------------- RMS + RoPE; q in-place, k packed to pk[h][s][d] ----------------
// NOTE: q is additionally scaled by (1/sqrt(128))*log2(e) = 0.12751745 so that
// flash_attn can use exp2 directly with NO per-element scale multiply.
__global__ __launch_bounds__(256) void rmsrope(bf16_t* __restrict__ qkv,
                                               bf16_t* __restrict__ pk,
                                               const float* __restrict__ gq,
                                               const float* __restrict__ gk,
                                               const float* __restrict__ freqs) {
  const int s = blockIdx.x, t = threadIdx.x;
  bf16_t* row = qkv + (size_t)s * QKVN;
  bf16x8 qv = *(const bf16x8*)&row[t * 8];
  bf16x8 kv = *(const bf16x8*)&row[2048 + t * 8];
  float qf[8], kf[8];
  float qs = 0.f, ks2 = 0.f;
#pragma unroll
  for (int i = 0; i < 8; i++) {
    qf[i] = (float)qv[i]; qs  += qf[i] * qf[i];
    kf[i] = (float)kv[i]; ks2 += kf[i] * kf[i];
  }
#pragma unroll
  for (int m = 1; m < 64; m <<= 1) {
    qs  += __shfl_xor(qs, m);
    ks2 += __shfl_xor(ks2, m);
  }
  __shared__ float red[2][4];
  const int wave = t >> 6, lane = t & 63;
  if (lane == 0) { red[0][wave] = qs; red[1][wave] = ks2; }
  __syncthreads();
  qs  = red[0][0] + red[0][1] + red[0][2] + red[0][3];
  ks2 = red[1][0] + red[1][1] + red[1][2] + red[1][3];
  const float qsc = rsqrtf(qs  / 2048.f + 1e-6f) * 0.12751745f; // fold attn scale*log2e
  const float ksc = rsqrtf(ks2 / 2048.f + 1e-6f);
  const int sf = s / 384, rem = s - sf * 384;
  const int sh = rem / 24, sw = rem - sh * 24;
  bf16x8 qo, ko;
#pragma unroll
  for (int u = 0; u < 4; u++) {
    const int col = t * 8 + 2 * u;
    const int i = (col >> 1) & 63;                         // pair index within head (c=64)
    const int frow = (i < 22) ? sf : ((i < 43) ? sh : sw); // cf=22, ch=cw=21
    const float ang = freqs[frow * 64 + i];
    float sn, cs;
    __sincosf(ang, &sn, &cs);
    float te = qf[2 * u]     * qsc * gq[col];
    float to = qf[2 * u + 1] * qsc * gq[col + 1];
    qo[2 * u]     = (bf16_t)(te * cs - to * sn);
    qo[2 * u + 1] = (bf16_t)(te * sn + to * cs);
    te = kf[2 * u]     * ksc * gk[col];
    to = kf[2 * u + 1] * ksc * gk[col + 1];
    ko[2 * u]     = (bf16_t)(te * cs - to * sn);
    ko[2 * u + 1] = (bf16_t)(te * sn + to * cs);
  }
  *(bf16x8*)&row[t * 8] = qo;
  // packed K: pk[h][s][d], h = t>>4, d = (t&15)*8
  *(bf16x8*)&pk[((size_t)(t >> 4) * SEQ + s) * HD + (t & 15) * 8] = ko;
}

// ---------------- V repack: fragment-major pvtf[h][kt][(c*4+dj)*32+l31] ----------------
__global__ __launch_bounds__(256) void vtrans(const bf16_t* __restrict__ qkv,
                                              bf16_t* __restrict__ pvtf) {
  __shared__ bf16_t tile[128][65];
  const int h = blockIdx.y;
  const int kt = blockIdx.x;        // one 64-kv flash tile per block
  const int s0 = kt * 64;
  const int t = threadIdx.x;
#pragma unroll
  for (int r = 0; r < 4; r++) {
    int L = r * 256 + t, s = L >> 4, cp = L & 15;
    bf16x8 v = *(const bf16x8*)&qkv[(size_t)(s0 + s) * QKVN + 4096 + h * HD + cp * 8];
#pragma unroll
    for (int i = 0; i < 8; i++) tile[cp * 8 + i][s] = v[i];
  }
  __syncthreads();
#pragma unroll
  for (int r = 0; r < 4; r++) {
    int L = r * 256 + t, c = L >> 7, d = L & 127;   // c: kv-chunk 0..7, d: 0..127
    bf16x8 o;
#pragma unroll
    for (int i = 0; i < 8; i++) o[i] = tile[d][c * 8 + i];
    *(bf16x8*)&pvtf[((size_t)h * 48 + kt) * 8192 + (size_t)(((c * 4 + (d >> 5)) * 32 + (d & 31)) * 8)] = o;
  }
}

// ---------------- Flash attention v8: V from L2, issue-order-pinned ----------------
// R8 failure mode (VGPR=128 proved it): compiler sank the 16 V loads to just before
// PV, and with staging issued first, waiting for V (newest in queue) forced vmcnt(0)
// -> drained next-tile K staging every iteration. Fix: V loads FIRST (oldest in the
// in-order vmcnt queue), sched_barrier(0) pins them, staging after. PV's auto-wait
// becomes a counted vmcnt(12) -> staging stays in flight across compute (T4).
#define STAGE_K(BUF, KV1) do {                                               \
    _Pragma("unroll")                                                        \
    for (int r = 0; r < 5; r++) {                                            \
      int L = r * 192 + t;                                                   \
      async16(pkh + (size_t)(KV1) * HD + koff[r], &Ks[BUF][L * 8]);          \
    }                                                                        \
    if (t < 64) {                                                            \
      int L = 960 + t;                                                       \
      async16(pkh + (size_t)(KV1) * HD + koff[5], &Ks[BUF][L * 8]);          \
    }                                                                        \
  } while (0)

__global__ __launch_bounds__(192, 2) void flash_attn(const bf16_t* __restrict__ qkv,
                                                     const bf16_t* __restrict__ pk,
                                                     const bf16_t* __restrict__ pvtf,
                                                     bf16_t* __restrict__ ob) {
  __shared__ __align__(16) bf16_t Ks[2][64 * 128];  // [kv][d], 16 chunks/row, xor-swizzled
  const int f = blockIdx.x;
  const int wg = (f & 7) * 64 + (f >> 3);           // XCD x owns wg in [x*64, x*64+63] = 2 heads
  const int hh = wg >> 5, qt = wg & 31;
  const int s0 = qt * 96;
  const int t = threadIdx.x, wave = t >> 6, lane = t & 63;
  const int l31 = lane & 31, hl = lane >> 5;
  const int wq = wave * 32;
  const bf16_t* pkh = pk + (size_t)hh * (SEQ * HD);
  int koff[6];
#pragma unroll
  for (int r = 0; r < 6; r++) {
    int L = r * 192 + t;
    int krow = L >> 4, kc = (L & 15) ^ (krow & 7);
    koff[r] = krow * HD + kc * 8;
  }
  // Q fragments (B-operand): lane holds Q[q=l31][d = ks*16 + hl*8 + j]
  bf16x8 qfr[8];
#pragma unroll
  for (int ks = 0; ks < 8; ks++)
    qfr[ks] = *(const bf16x8*)&qkv[(size_t)(s0 + wq + l31) * QKVN + hh * HD + ks * 16 + hl * 8];
  bf16x8 vones;
#pragma unroll
  for (int i = 0; i < 8; i++) vones[i] = (bf16_t)1.0f;
  f32x16 oacc[4] = {};  // O[q(per-reg)][d = dj*32 + l31]
  f32x16 lacc = {};     // row-sum of P, same q-per-reg layout
  STAGE_K(0, 0);
  for (int kt = 0; kt < SEQ / 64; kt++) {
    const int cur = kt & 1;
    __syncthreads();  // K tile kt landed; all waves done reading buf cur^1
    // 1) V fragments FIRST: 16 coalesced dwordx4 from L2 (oldest in vmcnt queue).
    const bf16_t* vfb = pvtf + ((size_t)hh * 48 + kt) * 8192;
    bf16x8 vf[4][4];
#pragma unroll
    for (int S = 0; S < 4; S++)
#pragma unroll
      for (int dj = 0; dj < 4; dj++)
        vf[S][dj] = *(const bf16x8*)&vfb[(size_t)((((S * 2 + hl) * 4 + dj) * 32 + l31) * 8)];
    __builtin_amdgcn_sched_barrier(0);  // pin V issues before staging (defeat sinking)
    // 2) next-tile K staging (12 async16) — newest in queue, stays in flight thru PV
    if (kt + 1 < SEQ / 64) STAGE_K(cur ^ 1, (kt + 1) * 64);
    __builtin_amdgcn_sched_barrier(0);
    // 3) S^T = K * Q^T: st0 = kv 0..31, st1 = kv 32..63; col = q = l31,
    // row(reg r) = (r&3) + 8*(r>>2) + 4*hl. Log2 domain (Q pre-scaled).
    f32x16 st0 = {}, st1 = {};
    __builtin_amdgcn_s_setprio(1);
#pragma unroll
    for (int ks = 0; ks < 8; ks++) {
      const int r1 = 32 + l31;
      bf16x8 k0 = *(const bf16x8*)&Ks[cur][l31 * 128 + (((ks * 2 + hl) ^ (l31 & 7)) * 8)];
      bf16x8 k1 = *(const bf16x8*)&Ks[cur][r1 * 128 + (((ks * 2 + hl) ^ (r1 & 7)) * 8)];
      st0 = __builtin_amdgcn_mfma_f32_32x32x16_bf16(k0, qfr[ks], st0, 0, 0, 0);
      st1 = __builtin_amdgcn_mfma_f32_32x32x16_bf16(k1, qfr[ks], st1, 0, 0, 0);
    }
    __builtin_amdgcn_s_setprio(0);
    // P = exp2(st), fixed m=0 (|st| <~ 8 in log2 domain; validated R3/R4/R6 absmax)
    uint32_t c0[8], c1[8];
#pragma unroll
    for (int m = 0; m < 8; m++) {
      bf16x2 w0, w1;
      w0[0] = (bf16_t)__builtin_amdgcn_exp2f(st0[2 * m]);
      w0[1] = (bf16_t)__builtin_amdgcn_exp2f(st0[2 * m + 1]);
      w1[0] = (bf16_t)__builtin_amdgcn_exp2f(st1[2 * m]);
      w1[1] = (bf16_t)__builtin_amdgcn_exp2f(st1[2 * m + 1]);
      c0[m] = __builtin_bit_cast(uint32_t, w0);
      c1[m] = __builtin_bit_cast(uint32_t, w1);
    }
    // Build PV A-fragments: afrS holds P[q=l31][kv = S*16 + hl*8 + j].
    union U8 { uint32_t u[4]; bf16x8 v; } afr0, afr1, afr2, afr3;
#define BUILD_AFR(DST, CB, B) do {                                           \
      uint32_t sA = hl ? CB[(B) + 0] : CB[(B) + 2];                          \
      uint32_t sB = hl ? CB[(B) + 1] : CB[(B) + 3];                          \
      uint32_t rA = (uint32_t)__shfl_xor((int)sA, 32);                       \
      uint32_t rB = (uint32_t)__shfl_xor((int)sB, 32);                       \
      DST.u[0] = hl ? rA : CB[(B) + 0];                                      \
      DST.u[1] = hl ? rB : CB[(B) + 1];                                      \
      DST.u[2] = hl ? CB[(B) + 2] : rA;                                      \
      DST.u[3] = hl ? CB[(B) + 3] : rB;                                      \
    } while (0)
    BUILD_AFR(afr0, c0, 0);
    BUILD_AFR(afr1, c0, 4);
    BUILD_AFR(afr2, c1, 0);
    BUILD_AFR(afr3, c1, 4);
#undef BUILD_AFR
    // O += P * V ; l += P * 1 (ones-column trick)
    __builtin_amdgcn_s_setprio(1);
#define PV_STEP(AFR, S) do {                                                            \
      lacc = __builtin_amdgcn_mfma_f32_32x32x16_bf16(AFR.v, vones, lacc, 0, 0, 0);      \
      _Pragma("unroll")                                                                 \
      for (int dj = 0; dj < 4; dj++)                                                    \
        oacc[dj] = __builtin_amdgcn_mfma_f32_32x32x16_bf16(AFR.v, vf[S][dj], oacc[dj], 0, 0, 0); \
    } while (0)
    PV_STEP(afr0, 0);
    PV_STEP(afr1, 1);
    PV_STEP(afr2, 2);
    PV_STEP(afr3, 3);
#undef PV_STEP
    __builtin_amdgcn_s_setprio(0);
  }
  // epilogue: divide by l (rows aligned with oacc), store bf16 into ob [s][n*d]
#pragma unroll
  for (int r = 0; r < 16; r++) {
    const float li = 1.f / lacc[r];
    const size_t row = (size_t)(s0 + wq + (r & 3) + 8 * (r >> 2) + 4 * hl);
#pragma unroll
    for (int dj = 0; dj < 4; dj++)
      ob[row * DIMD + hh * HD + dj * 32 + l31] = (bf16_t)(oacc[dj][r] * li);
  }
}

// ---------------- launch ----------------
extern "C" void kernel_launch(void* const* d_in, const int* in_sizes, int n_in,
                              void* d_out, int out_size, void* d_ws, size_t ws_size,
                              hipStream_t stream) {
  (void)in_sizes; (void)n_in; (void)out_size;
  const float* x     = (const float*)d_in[0];
  const float* freqs = (const float*)d_in[1];
  const float* Wq    = (const float*)d_in[2];
  const float* bq    = (const float*)d_in[3];
  const float* Wk    = (const float*)d_in[4];
  const float* bk    = (const float*)d_in[5];
  const float* Wv    = (const float*)d_in[6];
  const float* bv    = (const float*)d_in[7];
  const float* Wo    = (const float*)d_in[8];
  const float* bo    = (const float*)d_in[9];
  const float* gq    = (const float*)d_in[10];
  const float* gk    = (const float*)d_in[11];

  // workspace carve (bytes); [0, 37748736) holds xb+Wqkvb during gemm1,
  // reused afterwards for pk / pvtf.
  char* w = (char*)d_ws;
  bf16_t* xb    = (bf16_t*)(w);                 // x bf16:        12,582,912 B
  bf16_t* Wqkvb = (bf16_t*)(w + 12582912);      // Wq|Wk|Wv bf16: 25,165,824 B
  bf16_t* Wob   = (bf16_t*)(w + 37748736);      // Wo bf16:        8,388,608 B
  bf16_t* qkvb  = (bf16_t*)(w + 46137344);      // qkv bf16:      37,748,736 B
  bf16_t* obuf  = (bf16_t*)(w + 83886080);      // attn out bf16: 12,582,912 B
  float*  bqkv  = (float*) (w + 96468992);      // stacked bias:      24,576 B
  bf16_t* pk    = (bf16_t*)(w);                 // K packed [16][3072][128]: 12,582,912 B
  bf16_t* pvtf  = (bf16_t*)(w + 12582912);      // V fragment-major [16][48][8192]: 12,582,912 B
  if (ws_size < (size_t)96493568) return;

  // converts + bias pack (one launch)
  cvt_all<<<11288, 256, 0, stream>>>(x, Wq, Wk, Wv, Wo, bq, bk, bv, xb, Wqkvb, Wob, bqkv);

  // qkv = x @ [Wq;Wk;Wv]^T + bias   (3072 x 6144 x 2048)
  gemm_nt<true><<<dim3(48, 24), 256, 0, stream>>>(xb, Wqkvb, bqkv, qkvb, SEQ, QKVN, DIMD);
  // RMS(q,k) * g + grid RoPE; q in-place (pre-scaled by scale*log2e), k -> pk
  rmsrope<<<3072, 256, 0, stream>>>(qkvb, pk, gq, gk, freqs);
  // V repack -> fragment-major pvtf
  vtrans<<<dim3(48, NH), 256, 0, stream>>>(qkvb, pvtf);
  // attention (V from L2 issue-order-pinned, K in LDS, XCD head-clustering) -> obuf
  flash_attn<<<dim3(512), 192, 0, stream>>>(qkvb, pk, pvtf, obuf);
  // out = obuf @ Wo^T + bo  (3072 x 2048 x 2048), fp32 out
  gemm_nt<false><<<dim3(16, 24), 256, 0, stream>>>(obuf, Wob, bo, (float*)d_out, SEQ, DIMD, DIMD);
}

// Round 10
// 405.619 us; speedup vs baseline: 1.1967x; 1.1952x over previous
//
#include <hip/hip_runtime.h>
#include <stdint.h>
#include <stddef.h>

typedef __bf16 bf16_t;
typedef __bf16 bf16x8 __attribute__((ext_vector_type(8)));
typedef __bf16 bf16x4 __attribute__((ext_vector_type(4)));
typedef __bf16 bf16x2 __attribute__((ext_vector_type(2)));
typedef float  f32x4  __attribute__((ext_vector_type(4)));
typedef float  f32x16 __attribute__((ext_vector_type(16)));

#define SEQ   3072
#define DIMD  2048
#define NH    16
#define HD    128
#define QKVN  6144

__device__ __forceinline__ void async16(const bf16_t* g, bf16_t* l) {
  __builtin_amdgcn_global_load_lds((const __attribute__((address_space(1))) uint32_t*)g,
                                   (__attribute__((address_space(3))) uint32_t*)l, 16, 0, 0);
}

// ---------------- fused converts + bias pack (one launch) ----------------
__global__ __launch_bounds__(256) void cvt_all(const float* __restrict__ x,
                                               const float* __restrict__ Wq,
                                               const float* __restrict__ Wk,
                                               const float* __restrict__ Wv,
                                               const float* __restrict__ Wo,
                                               const float* __restrict__ bq,
                                               const float* __restrict__ bk,
                                               const float* __restrict__ bv,
                                               bf16_t* __restrict__ xb,
                                               bf16_t* __restrict__ Wqkvb,
                                               bf16_t* __restrict__ Wob,
                                               float* __restrict__ bqkv) {
  const int b = blockIdx.x;
  const float* src; bf16_t* dst; int off;
  if (b < 3072)       { src = x;  dst = xb;              off = b; }
  else if (b < 5120)  { src = Wq; dst = Wqkvb;           off = b - 3072; }
  else if (b < 7168)  { src = Wk; dst = Wqkvb + 4194304; off = b - 5120; }
  else if (b < 9216)  { src = Wv; dst = Wqkvb + 8388608; off = b - 7168; }
  else if (b < 11264) { src = Wo; dst = Wob;             off = b - 9216; }
  else {  // bias pack: 24 blocks cover 6144
    int t = (b - 11264) * 256 + threadIdx.x;
    float v;
    if (t < 2048)      v = bq[t];
    else if (t < 4096) v = bk[t - 2048];
    else               v = bv[t - 4096];
    bqkv[t] = v;
    return;
  }
  const int idx = (off * 256 + threadIdx.x) * 8;
  const float4 a = *(const float4*)(src + idx);
  const float4 c = *(const float4*)(src + idx + 4);
  bf16x8 o;
  o[0] = (bf16_t)a.x; o[1] = (bf16_t)a.y; o[2] = (bf16_t)a.z; o[3] = (bf16_t)a.w;
  o[4] = (bf16_t)c.x; o[5] = (bf16_t)c.y; o[6] = (bf16_t)c.z; o[7] = (bf16_t)c.w;
  *(bf16x8*)(dst + idx) = o;
}

// ---------------- GEMM: C[M,N] = A[M,K] * B[N,K]^T + bias (128^2 tile) ----------------
template<bool OUT_BF16>
__global__ __launch_bounds__(256, 3) void gemm_nt(const bf16_t* __restrict__ A,
                                                  const bf16_t* __restrict__ B,
                                                  const float* __restrict__ bias,
                                                  void* __restrict__ Cout,
                                                  int M, int N, int K) {
  __shared__ __align__(16) bf16_t As[128 * 64];
  __shared__ __align__(16) bf16_t Bs[128 * 64];
  const int t = threadIdx.x;
  const int lane = t & 63, wave = t >> 6;
  const int quad = lane >> 4, l15 = lane & 15;
  const int wy = wave >> 1, wx = wave & 1;
  const size_t bm = (size_t)blockIdx.y * 128, bn = (size_t)blockIdx.x * 128;
  const bf16_t* Ab = A + bm * K;
  const bf16_t* Bb = B + bn * K;
  f32x4 acc[4][4] = {};
  int srow[4], scol[4];
#pragma unroll
  for (int r = 0; r < 4; r++) {
    int L = r * 256 + t;
    int row = L >> 3, cp = L & 7;
    srow[r] = row;
    scol[r] = (cp ^ (row & 7)) * 8;
  }
  for (int k0 = 0; k0 < K; k0 += 64) {
    __syncthreads();
#pragma unroll
    for (int r = 0; r < 4; r++)
      async16(Ab + (size_t)srow[r] * K + k0 + scol[r], &As[(r * 256 + t) * 8]);
#pragma unroll
    for (int r = 0; r < 4; r++)
      async16(Bb + (size_t)srow[r] * K + k0 + scol[r], &Bs[(r * 256 + t) * 8]);
    __syncthreads();
#pragma unroll
    for (int ks = 0; ks < 2; ks++) {
      bf16x8 af[4], bfv[4];
#pragma unroll
      for (int i = 0; i < 4; i++) {
        int row = wy * 64 + i * 16 + l15;
        af[i] = *(const bf16x8*)&As[row * 64 + (((ks * 4 + quad) ^ (row & 7)) * 8)];
      }
#pragma unroll
      for (int j = 0; j < 4; j++) {
        int row = wx * 64 + j * 16 + l15;
        bfv[j] = *(const bf16x8*)&Bs[row * 64 + (((ks * 4 + quad) ^ (row & 7)) * 8)];
      }
#pragma unroll
      for (int i = 0; i < 4; i++)
#pragma unroll
        for (int j = 0; j < 4; j++)
          acc[i][j] = __builtin_amdgcn_mfma_f32_16x16x32_bf16(af[i], bfv[j], acc[i][j], 0, 0, 0);
    }
  }
#pragma unroll
  for (int i = 0; i < 4; i++) {
#pragma unroll
    for (int j = 0; j < 4; j++) {
      size_t row = bm + wy * 64 + i * 16 + quad * 4;
      size_t col = bn + wx * 64 + j * 16 + l15;
      float bb = bias[col];
#pragma unroll
      for (int r = 0; r < 4; r++) {
        float v = acc[i][j][r] + bb;
        if (OUT_BF16) ((bf16_t*)Cout)[(row + r) * N + col] = (bf16_t)v;
        else          ((float*)Cout)[(row + r) * N + col] = v;
      }
    }
  }
}

// ---------------- fused prep: RMS+RoPE (blocks 0..3071) | V transpose (blocks 3072..3839) ----------------
// The two phases touch disjoint data (q/k thirds + pk vs the V third + pvt), so one
// combined launch removes a kernel-launch gap and overlaps their memory traffic.
// q is pre-scaled by (1/sqrt(128))*log2(e) = 0.12751745 so flash uses exp2 directly.
__global__ __launch_bounds__(256) void prep(bf16_t* __restrict__ qkv,
                                            bf16_t* __restrict__ pk,
                                            bf16_t* __restrict__ pvt,
                                            const float* __restrict__ gq,
                                            const float* __restrict__ gk,
                                            const float* __restrict__ freqs) {
  __shared__ bf16_t tile[128][65];
  __shared__ float red[2][4];
  const int t = threadIdx.x;
  if (blockIdx.x < 3072) {
    // ---- RMS + RoPE ----
    const int s = blockIdx.x;
    bf16_t* row = qkv + (size_t)s * QKVN;
    bf16x8 qv = *(const bf16x8*)&row[t * 8];
    bf16x8 kv = *(const bf16x8*)&row[2048 + t * 8];
    float qf[8], kf[8];
    float qs = 0.f, ks2 = 0.f;
#pragma unroll
    for (int i = 0; i < 8; i++) {
      qf[i] = (float)qv[i]; qs  += qf[i] * qf[i];
      kf[i] = (float)kv[i]; ks2 += kf[i] * kf[i];
    }
#pragma unroll
    for (int m = 1; m < 64; m <<= 1) {
      qs  += __shfl_xor(qs, m);
      ks2 += __shfl_xor(ks2, m);
    }
    const int wave = t >> 6, lane = t & 63;
    if (lane == 0) { red[0][wave] = qs; red[1][wave] = ks2; }
    __syncthreads();
    qs  = red[0][0] + red[0][1] + red[0][2] + red[0][3];
    ks2 = red[1][0] + red[1][1] + red[1][2] + red[1][3];
    const float qsc = rsqrtf(qs  / 2048.f + 1e-6f) * 0.12751745f; // fold attn scale*log2e
    const float ksc = rsqrtf(ks2 / 2048.f + 1e-6f);
    const int sf = s / 384, rem = s - sf * 384;
    const int sh = rem / 24, sw = rem - sh * 24;
    bf16x8 qo, ko;
#pragma unroll
    for (int u = 0; u < 4; u++) {
      const int col = t * 8 + 2 * u;
      const int i = (col >> 1) & 63;                         // pair index within head (c=64)
      const int frow = (i < 22) ? sf : ((i < 43) ? sh : sw); // cf=22, ch=cw=21
      const float ang = freqs[frow * 64 + i];
      float sn, cs;
      __sincosf(ang, &sn, &cs);
      float te = qf[2 * u]     * qsc * gq[col];
      float to = qf[2 * u + 1] * qsc * gq[col + 1];
      qo[2 * u]     = (bf16_t)(te * cs - to * sn);
      qo[2 * u + 1] = (bf16_t)(te * sn + to * cs);
      te = kf[2 * u]     * ksc * gk[col];
      to = kf[2 * u + 1] * ksc * gk[col + 1];
      ko[2 * u]     = (bf16_t)(te * cs - to * sn);
      ko[2 * u + 1] = (bf16_t)(te * sn + to * cs);
    }
    *(bf16x8*)&row[t * 8] = qo;
    // packed K: pk[h][s][d], h = t>>4, d = (t&15)*8
    *(bf16x8*)&pk[((size_t)(t >> 4) * SEQ + s) * HD + (t & 15) * 8] = ko;
  } else {
    // ---- V transpose: pvt[h][d][s] ----
    const int idx = blockIdx.x - 3072;
    const int h = idx / 48;
    const int s0 = (idx - h * 48) * 64;
#pragma unroll
    for (int r = 0; r < 4; r++) {
      int L = r * 256 + t, s = L >> 4, cp = L & 15;
      bf16x8 v = *(const bf16x8*)&qkv[(size_t)(s0 + s) * QKVN + 4096 + h * HD + cp * 8];
#pragma unroll
      for (int i = 0; i < 8; i++) tile[cp * 8 + i][s] = v[i];
    }
    __syncthreads();
#pragma unroll
    for (int r = 0; r < 4; r++) {
      int L = r * 256 + t, d = L >> 3, c = L & 7;
      bf16x8 o;
#pragma unroll
      for (int i = 0; i < 8; i++) o[i] = tile[d][c * 8 + i];
      *(bf16x8*)&pvt[((size_t)h * HD + d) * SEQ + s0 + c * 8] = o;
    }
  }
}

// ---------------- Flash attention (R6 config: fixed-m, best measured 117.3us) ----------------
// 32x32x16 MFMA, in-register P, grid dim3(32,16) = 512 blocks x 3 waves, 2 blocks/CU.
#define STAGE_KV(BUF, KV1) do {                                              \
    _Pragma("unroll")                                                        \
    for (int r = 0; r < 5; r++) {                                            \
      int L = r * 192 + t;                                                   \
      async16(pkh + (size_t)(KV1) * HD + koff[r], &Ks[BUF][L * 8]);          \
      async16(pvh + (KV1) + voff[r], &Vt[BUF][L * 8]);                       \
    }                                                                        \
    if (t < 64) {                                                            \
      int L = 5 * 192 + t;                                                   \
      async16(pkh + (size_t)(KV1) * HD + koff[5], &Ks[BUF][L * 8]);          \
      async16(pvh + (KV1) + voff[5], &Vt[BUF][L * 8]);                       \
    }                                                                        \
  } while (0)

__global__ __launch_bounds__(192, 2) void flash_attn(const bf16_t* __restrict__ qkv,
                                                     const bf16_t* __restrict__ pk,
                                                     const bf16_t* __restrict__ pvt,
                                                     bf16_t* __restrict__ ob) {
  __shared__ __align__(16) bf16_t Ks[2][64 * 128];  // [kv][d], 16 chunks/row, xor-swizzled
  __shared__ __align__(16) bf16_t Vt[2][128 * 64];  // [d][kv], 8 chunks/row, xor-swizzled
  const int hh = blockIdx.y, qt = blockIdx.x;
  const int s0 = qt * 96;
  const int t = threadIdx.x, wave = t >> 6, lane = t & 63;
  const int l31 = lane & 31, hl = lane >> 5;
  const int wq = wave * 32;
  const bf16_t* pkh = pk  + (size_t)hh * (SEQ * HD);
  const bf16_t* pvh = pvt + (size_t)hh * (HD * SEQ);
  int koff[6], voff[6];
#pragma unroll
  for (int r = 0; r < 6; r++) {
    int L = r * 192 + t;
    int krow = L >> 4, kc = (L & 15) ^ (krow & 7);
    koff[r] = krow * HD + kc * 8;
    int vd = L >> 3, vc = (L & 7) ^ (vd & 7);
    voff[r] = vd * SEQ + vc * 8;
  }
  // Q fragments (B-operand): lane holds Q[q=l31][d = ks*16 + hl*8 + j]
  bf16x8 qfr[8];
#pragma unroll
  for (int ks = 0; ks < 8; ks++)
    qfr[ks] = *(const bf16x8*)&qkv[(size_t)(s0 + wq + l31) * QKVN + hh * HD + ks * 16 + hl * 8];
  bf16x8 vones;
#pragma unroll
  for (int i = 0; i < 8; i++) vones[i] = (bf16_t)1.0f;
  f32x16 oacc[4] = {};  // O[q(per-reg)][d = dj*32 + l31]
  f32x16 lacc = {};     // row-sum of P, same q-per-reg layout
  STAGE_KV(0, 0);
  for (int kt = 0; kt < SEQ / 64; kt++) {
    const int cur = kt & 1;
    __syncthreads();  // tile kt landed; all waves done reading buf cur^1
    if (kt + 1 < SEQ / 64) STAGE_KV(cur ^ 1, (kt + 1) * 64);
    // S^T = K * Q^T: st0 = kv 0..31, st1 = kv 32..63; col = q = l31,
    // row(reg r) = (r&3) + 8*(r>>2) + 4*hl. Log2 domain (Q pre-scaled).
    f32x16 st0 = {}, st1 = {};
    __builtin_amdgcn_s_setprio(1);
#pragma unroll
    for (int ks = 0; ks < 8; ks++) {
      const int r1 = 32 + l31;
      bf16x8 k0 = *(const bf16x8*)&Ks[cur][l31 * 128 + (((ks * 2 + hl) ^ (l31 & 7)) * 8)];
      bf16x8 k1 = *(const bf16x8*)&Ks[cur][r1 * 128 + (((ks * 2 + hl) ^ (r1 & 7)) * 8)];
      st0 = __builtin_amdgcn_mfma_f32_32x32x16_bf16(k0, qfr[ks], st0, 0, 0, 0);
      st1 = __builtin_amdgcn_mfma_f32_32x32x16_bf16(k1, qfr[ks], st1, 0, 0, 0);
    }
    __builtin_amdgcn_s_setprio(0);
    // P = exp2(st), fixed m=0 (|st| <~ 8 in log2 domain; validated R3/R4/R6 absmax)
    uint32_t c0[8], c1[8];
#pragma unroll
    for (int m = 0; m < 8; m++) {
      bf16x2 w0, w1;
      w0[0] = (bf16_t)__builtin_amdgcn_exp2f(st0[2 * m]);
      w0[1] = (bf16_t)__builtin_amdgcn_exp2f(st0[2 * m + 1]);
      w1[0] = (bf16_t)__builtin_amdgcn_exp2f(st1[2 * m]);
      w1[1] = (bf16_t)__builtin_amdgcn_exp2f(st1[2 * m + 1]);
      c0[m] = __builtin_bit_cast(uint32_t, w0);
      c1[m] = __builtin_bit_cast(uint32_t, w1);
    }
    // Build PV A-fragments: afrS holds P[q=l31][kv = S*16 + hl*8 + j].
    union U8 { uint32_t u[4]; bf16x8 v; } afr0, afr1, afr2, afr3;
#define BUILD_AFR(DST, CB, B) do {                                           \
      uint32_t sA = hl ? CB[(B) + 0] : CB[(B) + 2];                          \
      uint32_t sB = hl ? CB[(B) + 1] : CB[(B) + 3];                          \
      uint32_t rA = (uint32_t)__shfl_xor((int)sA, 32);                       \
      uint32_t rB = (uint32_t)__shfl_xor((int)sB, 32);                       \
      DST.u[0] = hl ? rA : CB[(B) + 0];                                      \
      DST.u[1] = hl ? rB : CB[(B) + 1];                                      \
      DST.u[2] = hl ? CB[(B) + 2] : rA;                                      \
      DST.u[3] = hl ? CB[(B) + 3] : rB;                                      \
    } while (0)
    BUILD_AFR(afr0, c0, 0);
    BUILD_AFR(afr1, c0, 4);
    BUILD_AFR(afr2, c1, 0);
    BUILD_AFR(afr3, c1, 4);
#undef BUILD_AFR
    // O += P * V ; l += P * 1 (ones-column trick)
    __builtin_amdgcn_s_setprio(1);
#define PV_STEP(AFR, S) do {                                                            \
      lacc = __builtin_amdgcn_mfma_f32_32x32x16_bf16(AFR.v, vones, lacc, 0, 0, 0);      \
      _Pragma("unroll")                                                                 \
      for (int dj = 0; dj < 4; dj++) {                                                  \
        const int row = dj * 32 + l31;                                                  \
        bf16x8 vf = *(const bf16x8*)&Vt[cur][row * 64 + ((((S) * 2 + hl) ^ (row & 7)) * 8)]; \
        oacc[dj] = __builtin_amdgcn_mfma_f32_32x32x16_bf16(AFR.v, vf, oacc[dj], 0, 0, 0);    \
      }                                                                                 \
    } while (0)
    PV_STEP(afr0, 0);
    PV_STEP(afr1, 1);
    PV_STEP(afr2, 2);
    PV_STEP(afr3, 3);
#undef PV_STEP
    __builtin_amdgcn_s_setprio(0);
  }
  // epilogue: divide by l (rows aligned with oacc), store bf16 into ob [s][n*d]
#pragma unroll
  for (int r = 0; r < 16; r++) {
    const float li = 1.f / lacc[r];
    const size_t row = (size_t)(s0 + wq + (r & 3) + 8 * (r >> 2) + 4 * hl);
#pragma unroll
    for (int dj = 0; dj < 4; dj++)
      ob[row * DIMD + hh * HD + dj * 32 + l31] = (bf16_t)(oacc[dj][r] * li);
  }
}

// ---------------- launch ----------------
extern "C" void kernel_launch(void* const* d_in, const int* in_sizes, int n_in,
                              void* d_out, int out_size, void* d_ws, size_t ws_size,
                              hipStream_t stream) {
  (void)in_sizes; (void)n_in; (void)out_size;
  const float* x     = (const float*)d_in[0];
  const float* freqs = (const float*)d_in[1];
  const float* Wq    = (const float*)d_in[2];
  const float* bq    = (const float*)d_in[3];
  const float* Wk    = (const float*)d_in[4];
  const float* bk    = (const float*)d_in[5];
  const float* Wv    = (const float*)d_in[6];
  const float* bv    = (const float*)d_in[7];
  const float* Wo    = (const float*)d_in[8];
  const float* bo    = (const float*)d_in[9];
  const float* gq    = (const float*)d_in[10];
  const float* gk    = (const float*)d_in[11];

  // workspace carve (bytes); [0, 37748736) holds xb+Wqkvb during gemm1,
  // reused afterwards for pk / pvt.
  char* w = (char*)d_ws;
  bf16_t* xb    = (bf16_t*)(w);                 // x bf16:        12,582,912 B
  bf16_t* Wqkvb = (bf16_t*)(w + 12582912);      // Wq|Wk|Wv bf16: 25,165,824 B
  bf16_t* Wob   = (bf16_t*)(w + 37748736);      // Wo bf16:        8,388,608 B
  bf16_t* qkvb  = (bf16_t*)(w + 46137344);      // qkv bf16:      37,748,736 B
  bf16_t* obuf  = (bf16_t*)(w + 83886080);      // attn out bf16: 12,582,912 B
  float*  bqkv  = (float*) (w + 96468992);      // stacked bias:      24,576 B
  bf16_t* pk    = (bf16_t*)(w);                 // K packed [16][3072][128]: 12,582,912 B
  bf16_t* pvt   = (bf16_t*)(w + 12582912);      // V^T [16][128][3072]:      12,582,912 B
  if (ws_size < (size_t)96493568) return;

  // converts + bias pack (one launch)
  cvt_all<<<11288, 256, 0, stream>>>(x, Wq, Wk, Wv, Wo, bq, bk, bv, xb, Wqkvb, Wob, bqkv);

  // qkv = x @ [Wq;Wk;Wv]^T + bias   (3072 x 6144 x 2048)
  gemm_nt<true><<<dim3(48, 24), 256, 0, stream>>>(xb, Wqkvb, bqkv, qkvb, SEQ, QKVN, DIMD);
  // fused RMS+RoPE (q in-place, k -> pk) and V transpose (-> pvt), one launch
  prep<<<3840, 256, 0, stream>>>(qkvb, pk, pvt, gq, gk, freqs);
  // attention (fixed-m, 32x32 MFMA, in-register P) -> obuf
  flash_attn<<<dim3(32, NH), 192, 0, stream>>>(qkvb, pk, pvt, obuf);
  // out = obuf @ Wo^T + bo  (3072 x 2048 x 2048), fp32 out
  gemm_nt<false><<<dim3(16, 24), 256, 0, stream>>>(obuf, Wob, bo, (float*)d_out, SEQ, DIMD, DIMD);
}

// Round 12
// 404.590 us; speedup vs baseline: 1.1998x; 1.0025x over previous
//
#include <hip/hip_runtime.h>
#include <stdint.h>
#include <stddef.h>

typedef __bf16 bf16_t;
typedef __bf16 bf16x8 __attribute__((ext_vector_type(8)));
typedef __bf16 bf16x4 __attribute__((ext_vector_type(4)));
typedef __bf16 bf16x2 __attribute__((ext_vector_type(2)));
typedef float  f32x4  __attribute__((ext_vector_type(4)));
typedef float  f32x16 __attribute__((ext_vector_type(16)));

#define SEQ   3072
#define DIMD  2048
#define NH    16
#define HD    128
#define QKVN  6144

__device__ __forceinline__ void async16(const bf16_t* g, bf16_t* l) {
  __builtin_amdgcn_global_load_lds((const __attribute__((address_space(1))) uint32_t*)g,
                                   (__attribute__((address_space(3))) uint32_t*)l, 16, 0, 0);
}

// ---------------- fused converts + bias pack (one launch) ----------------
__global__ __launch_bounds__(256) void cvt_all(const float* __restrict__ x,
                                               const float* __restrict__ Wq,
                                               const float* __restrict__ Wk,
                                               const float* __restrict__ Wv,
                                               const float* __restrict__ Wo,
                                               const float* __restrict__ bq,
                                               const float* __restrict__ bk,
                                               const float* __restrict__ bv,
                                               bf16_t* __restrict__ xb,
                                               bf16_t* __restrict__ Wqkvb,
                                               bf16_t* __restrict__ Wob,
                                               float* __restrict__ bqkv) {
  const int b = blockIdx.x;
  const float* src; bf16_t* dst; int off;
  if (b < 3072)       { src = x;  dst = xb;              off = b; }
  else if (b < 5120)  { src = Wq; dst = Wqkvb;           off = b - 3072; }
  else if (b < 7168)  { src = Wk; dst = Wqkvb + 4194304; off = b - 5120; }
  else if (b < 9216)  { src = Wv; dst = Wqkvb + 8388608; off = b - 7168; }
  else if (b < 11264) { src = Wo; dst = Wob;             off = b - 9216; }
  else {  // bias pack: 24 blocks cover 6144
    int t = (b - 11264) * 256 + threadIdx.x;
    float v;
    if (t < 2048)      v = bq[t];
    else if (t < 4096) v = bk[t - 2048];
    else               v = bv[t - 4096];
    bqkv[t] = v;
    return;
  }
  const int idx = (off * 256 + threadIdx.x) * 8;
  const float4 a = *(const float4*)(src + idx);
  const float4 c = *(const float4*)(src + idx + 4);
  bf16x8 o;
  o[0] = (bf16_t)a.x; o[1] = (bf16_t)a.y; o[2] = (bf16_t)a.z; o[3] = (bf16_t)a.w;
  o[4] = (bf16_t)c.x; o[5] = (bf16_t)c.y; o[6] = (bf16_t)c.z; o[7] = (bf16_t)c.w;
  *(bf16x8*)(dst + idx) = o;
}

// ---------------- GEMM: C[M,N] = A[M,K] * B[N,K]^T + bias (128^2 tile) ----------------
template<bool OUT_BF16>
__global__ __launch_bounds__(256, 3) void gemm_nt(const bf16_t* __restrict__ A,
                                                  const bf16_t* __restrict__ B,
                                                  const float* __restrict__ bias,
                                                  void* __restrict__ Cout,
                                                  int M, int N, int K) {
  __shared__ __align__(16) bf16_t As[128 * 64];
  __shared__ __align__(16) bf16_t Bs[128 * 64];
  const int t = threadIdx.x;
  const int lane = t & 63, wave = t >> 6;
  const int quad = lane >> 4, l15 = lane & 15;
  const int wy = wave >> 1, wx = wave & 1;
  const size_t bm = (size_t)blockIdx.y * 128, bn = (size_t)blockIdx.x * 128;
  const bf16_t* Ab = A + bm * K;
  const bf16_t* Bb = B + bn * K;
  f32x4 acc[4][4] = {};
  int srow[4], scol[4];
#pragma unroll
  for (int r = 0; r < 4; r++) {
    int L = r * 256 + t;
    int row = L >> 3, cp = L & 7;
    srow[r] = row;
    scol[r] = (cp ^ (row & 7)) * 8;
  }
  for (int k0 = 0; k0 < K; k0 += 64) {
    __syncthreads();
#pragma unroll
    for (int r = 0; r < 4; r++)
      async16(Ab + (size_t)srow[r] * K + k0 + scol[r], &As[(r * 256 + t) * 8]);
#pragma unroll
    for (int r = 0; r < 4; r++)
      async16(Bb + (size_t)srow[r] * K + k0 + scol[r], &Bs[(r * 256 + t) * 8]);
    __syncthreads();
#pragma unroll
    for (int ks = 0; ks < 2; ks++) {
      bf16x8 af[4], bfv[4];
#pragma unroll
      for (int i = 0; i < 4; i++) {
        int row = wy * 64 + i * 16 + l15;
        af[i] = *(const bf16x8*)&As[row * 64 + (((ks * 4 + quad) ^ (row & 7)) * 8)];
      }
#pragma unroll
      for (int j = 0; j < 4; j++) {
        int row = wx * 64 + j * 16 + l15;
        bfv[j] = *(const bf16x8*)&Bs[row * 64 + (((ks * 4 + quad) ^ (row & 7)) * 8)];
      }
#pragma unroll
      for (int i = 0; i < 4; i++)
#pragma unroll
        for (int j = 0; j < 4; j++)
          acc[i][j] = __builtin_amdgcn_mfma_f32_16x16x32_bf16(af[i], bfv[j], acc[i][j], 0, 0, 0);
    }
  }
#pragma unroll
  for (int i = 0; i < 4; i++) {
#pragma unroll
    for (int j = 0; j < 4; j++) {
      size_t row = bm + wy * 64 + i * 16 + quad * 4;
      size_t col = bn + wx * 64 + j * 16 + l15;
      float bb = bias[col];
#pragma unroll
      for (int r = 0; r < 4; r++) {
        float v = acc[i][j][r] + bb;
        if (OUT_BF16) ((bf16_t*)Cout)[(row + r) * N + col] = (bf16_t)v;
        else          ((float*)Cout)[(row + r) * N + col] = v;
      }
    }
  }
}

// ---------------- fused prep: RMS+RoPE (blocks 0..3071) | V transpose (blocks 3072..3839) ----------------
// q is pre-scaled by (1/sqrt(128))*log2(e) = 0.12751745 so flash uses exp2 directly.
__global__ __launch_bounds__(256) void prep(bf16_t* __restrict__ qkv,
                                            bf16_t* __restrict__ pk,
                                            bf16_t* __restrict__ pvt,
                                            const float* __restrict__ gq,
                                            const float* __restrict__ gk,
                                            const float* __restrict__ freqs) {
  __shared__ bf16_t tile[128][65];
  __shared__ float red[2][4];
  const int t = threadIdx.x;
  if (blockIdx.x < 3072) {
    // ---- RMS + RoPE ----
    const int s = blockIdx.x;
    bf16_t* row = qkv + (size_t)s * QKVN;
    bf16x8 qv = *(const bf16x8*)&row[t * 8];
    bf16x8 kv = *(const bf16x8*)&row[2048 + t * 8];
    float qf[8], kf[8];
    float qs = 0.f, ks2 = 0.f;
#pragma unroll
    for (int i = 0; i < 8; i++) {
      qf[i] = (float)qv[i]; qs  += qf[i] * qf[i];
      kf[i] = (float)kv[i]; ks2 += kf[i] * kf[i];
    }
#pragma unroll
    for (int m = 1; m < 64; m <<= 1) {
      qs  += __shfl_xor(qs, m);
      ks2 += __shfl_xor(ks2, m);
    }
    const int wave = t >> 6, lane = t & 63;
    if (lane == 0) { red[0][wave] = qs; red[1][wave] = ks2; }
    __syncthreads();
    qs  = red[0][0] + red[0][1] + red[0][2] + red[0][3];
    ks2 = red[1][0] + red[1][1] + red[1][2] + red[1][3];
    const float qsc = rsqrtf(qs  / 2048.f + 1e-6f) * 0.12751745f; // fold attn scale*log2e
    const float ksc = rsqrtf(ks2 / 2048.f + 1e-6f);
    const int sf = s / 384, rem = s - sf * 384;
    const int sh = rem / 24, sw = rem - sh * 24;
    bf16x8 qo, ko;
#pragma unroll
    for (int u = 0; u < 4; u++) {
      const int col = t * 8 + 2 * u;
      const int i = (col >> 1) & 63;                         // pair index within head (c=64)
      const int frow = (i < 22) ? sf : ((i < 43) ? sh : sw); // cf=22, ch=cw=21
      const float ang = freqs[frow * 64 + i];
      float sn, cs;
      __sincosf(ang, &sn, &cs);
      float te = qf[2 * u]     * qsc * gq[col];
      float to = qf[2 * u + 1] * qsc * gq[col + 1];
      qo[2 * u]     = (bf16_t)(te * cs - to * sn);
      qo[2 * u + 1] = (bf16_t)(te * sn + to * cs);
      te = kf[2 * u]     * ksc * gk[col];
      to = kf[2 * u + 1] * ksc * gk[col + 1];
      ko[2 * u]     = (bf16_t)(te * cs - to * sn);
      ko[2 * u + 1] = (bf16_t)(te * sn + to * cs);
    }
    *(bf16x8*)&row[t * 8] = qo;
    // packed K: pk[h][s][d], h = t>>4, d = (t&15)*8
    *(bf16x8*)&pk[((size_t)(t >> 4) * SEQ + s) * HD + (t & 15) * 8] = ko;
  } else {
    // ---- V transpose: pvt[h][d][s] ----
    const int idx = blockIdx.x - 3072;
    const int h = idx / 48;
    const int s0 = (idx - h * 48) * 64;
#pragma unroll
    for (int r = 0; r < 4; r++) {
      int L = r * 256 + t, s = L >> 4, cp = L & 15;
      bf16x8 v = *(const bf16x8*)&qkv[(size_t)(s0 + s) * QKVN + 4096 + h * HD + cp * 8];
#pragma unroll
      for (int i = 0; i < 8; i++) tile[cp * 8 + i][s] = v[i];
    }
    __syncthreads();
#pragma unroll
    for (int r = 0; r < 4; r++) {
      int L = r * 256 + t, d = L >> 3, c = L & 7;
      bf16x8 o;
#pragma unroll
      for (int i = 0; i < 8; i++) o[i] = tile[d][c * 8 + i];
      *(bf16x8*)&pvt[((size_t)h * HD + d) * SEQ + s0 + c * 8] = o;
    }
  }
}

// ---------------- Flash attention (R6 internals + T1 XCD head-clustering) ----------------
// 32x32x16 MFMA, in-register P, fixed-m. Grid 512 x 192thr, 2 blocks/CU.
// Swizzle wg=(f&7)*64+(f>>3): each XCD owns 64 consecutive wg = exactly 2 heads ->
// that head pair's K+V (3MB) stays resident in the XCD's 4MB L2 (R8 proved the
// mechanism: FETCH 104 -> 22MB on this grid).
#define STAGE_KV(BUF, KV1) do {                                              \
    _Pragma("unroll")                                                        \
    for (int r = 0; r < 5; r++) {                                            \
      int L = r * 192 + t;                                                   \
      async16(pkh + (size_t)(KV1) * HD + koff[r], &Ks[BUF][L * 8]);          \
      async16(pvh + (KV1) + voff[r], &Vt[BUF][L * 8]);                       \
    }                                                                        \
    if (t < 64) {                                                            \
      int L = 5 * 192 + t;                                                   \
      async16(pkh + (size_t)(KV1) * HD + koff[5], &Ks[BUF][L * 8]);          \
      async16(pvh + (KV1) + voff[5], &Vt[BUF][L * 8]);                       \
    }                                                                        \
  } while (0)

__global__ __launch_bounds__(192, 2) void flash_attn(const bf16_t* __restrict__ qkv,
                                                     const bf16_t* __restrict__ pk,
                                                     const bf16_t* __restrict__ pvt,
                                                     bf16_t* __restrict__ ob) {
  __shared__ __align__(16) bf16_t Ks[2][64 * 128];  // [kv][d], 16 chunks/row, xor-swizzled
  __shared__ __align__(16) bf16_t Vt[2][128 * 64];  // [d][kv], 8 chunks/row, xor-swizzled
  const int f = blockIdx.x;
  const int wg = (f & 7) * 64 + (f >> 3);   // XCD x owns wg in [x*64, x*64+63] = 2 heads
  const int hh = wg >> 5, qt = wg & 31;
  const int s0 = qt * 96;
  const int t = threadIdx.x, wave = t >> 6, lane = t & 63;
  const int l31 = lane & 31, hl = lane >> 5;
  const int wq = wave * 32;
  const bf16_t* pkh = pk  + (size_t)hh * (SEQ * HD);
  const bf16_t* pvh = pvt + (size_t)hh * (HD * SEQ);
  int koff[6], voff[6];
#pragma unroll
  for (int r = 0; r < 6; r++) {
    int L = r * 192 + t;
    int krow = L >> 4, kc = (L & 15) ^ (krow & 7);
    koff[r] = krow * HD + kc * 8;
    int vd = L >> 3, vc = (L & 7) ^ (vd & 7);
    voff[r] = vd * SEQ + vc * 8;
  }
  // Q fragments (B-operand): lane holds Q[q=l31][d = ks*16 + hl*8 + j]
  bf16x8 qfr[8];
#pragma unroll
  for (int ks = 0; ks < 8; ks++)
    qfr[ks] = *(const bf16x8*)&qkv[(size_t)(s0 + wq + l31) * QKVN + hh * HD + ks * 16 + hl * 8];
  bf16x8 vones;
#pragma unroll
  for (int i = 0; i < 8; i++) vones[i] = (bf16_t)1.0f;
  f32x16 oacc[4] = {};  // O[q(per-reg)][d = dj*32 + l31]
  f32x16 lacc = {};     // row-sum of P, same q-per-reg layout
  STAGE_KV(0, 0);
  for (int kt = 0; kt < SEQ / 64; kt++) {
    const int cur = kt & 1;
    __syncthreads();  // tile kt landed; all waves done reading buf cur^1
    if (kt + 1 < SEQ / 64) STAGE_KV(cur ^ 1, (kt + 1) * 64);
    // S^T = K * Q^T: st0 = kv 0..31, st1 = kv 32..63; col = q = l31,
    // row(reg r) = (r&3) + 8*(r>>2) + 4*hl. Log2 domain (Q pre-scaled).
    f32x16 st0 = {}, st1 = {};
    __builtin_amdgcn_s_setprio(1);
#pragma unroll
    for (int ks = 0; ks < 8; ks++) {
      const int r1 = 32 + l31;
      bf16x8 k0 = *(const bf16x8*)&Ks[cur][l31 * 128 + (((ks * 2 + hl) ^ (l31 & 7)) * 8)];
      bf16x8 k1 = *(const bf16x8*)&Ks[cur][r1 * 128 + (((ks * 2 + hl) ^ (r1 & 7)) * 8)];
      st0 = __builtin_amdgcn_mfma_f32_32x32x16_bf16(k0, qfr[ks], st0, 0, 0, 0);
      st1 = __builtin_amdgcn_mfma_f32_32x32x16_bf16(k1, qfr[ks], st1, 0, 0, 0);
    }
    __builtin_amdgcn_s_setprio(0);
    // P = exp2(st), fixed m=0 (|st| <~ 8 in log2 domain; validated R3/R4/R6 absmax)
    uint32_t c0[8], c1[8];
#pragma unroll
    for (int m = 0; m < 8; m++) {
      bf16x2 w0, w1;
      w0[0] = (bf16_t)__builtin_amdgcn_exp2f(st0[2 * m]);
      w0[1] = (bf16_t)__builtin_amdgcn_exp2f(st0[2 * m + 1]);
      w1[0] = (bf16_t)__builtin_amdgcn_exp2f(st1[2 * m]);
      w1[1] = (bf16_t)__builtin_amdgcn_exp2f(st1[2 * m + 1]);
      c0[m] = __builtin_bit_cast(uint32_t, w0);
      c1[m] = __builtin_bit_cast(uint32_t, w1);
    }
    // Build PV A-fragments: afrS holds P[q=l31][kv = S*16 + hl*8 + j].
    union U8 { uint32_t u[4]; bf16x8 v; } afr0, afr1, afr2, afr3;
#define BUILD_AFR(DST, CB, B) do {                                           \
      uint32_t sA = hl ? CB[(B) + 0] : CB[(B) + 2];                          \
      uint32_t sB = hl ? CB[(B) + 1] : CB[(B) + 3];                          \
      uint32_t rA = (uint32_t)__shfl_xor((int)sA, 32);                       \
      uint32_t rB = (uint32_t)__shfl_xor((int)sB, 32);                       \
      DST.u[0] = hl ? rA : CB[(B) + 0];                                      \
      DST.u[1] = hl ? rB : CB[(B) + 1];                                      \
      DST.u[2] = hl ? CB[(B) + 2] : rA;                                      \
      DST.u[3] = hl ? CB[(B) + 3] : rB;                                      \
    } while (0)
    BUILD_AFR(afr0, c0, 0);
    BUILD_AFR(afr1, c0, 4);
    BUILD_AFR(afr2, c1, 0);
    BUILD_AFR(afr3, c1, 4);
#undef BUILD_AFR
    // O += P * V ; l += P * 1 (ones-column trick)
    __builtin_amdgcn_s_setprio(1);
#define PV_STEP(AFR, S) do {                                                            \
      lacc = __builtin_amdgcn_mfma_f32_32x32x16_bf16(AFR.v, vones, lacc, 0, 0, 0);      \
      _Pragma("unroll")                                                                 \
      for (int dj = 0; dj < 4; dj++) {                                                  \
        const int row = dj * 32 + l31;                                                  \
        bf16x8 vf = *(const bf16x8*)&Vt[cur][row * 64 + ((((S) * 2 + hl) ^ (row & 7)) * 8)]; \
        oacc[dj] = __builtin_amdgcn_mfma_f32_32x32x16_bf16(AFR.v, vf, oacc[dj], 0, 0, 0);    \
      }                                                                                 \
    } while (0)
    PV_STEP(afr0, 0);
    PV_STEP(afr1, 1);
    PV_STEP(afr2, 2);
    PV_STEP(afr3, 3);
#undef PV_STEP
    __builtin_amdgcn_s_setprio(0);
  }
  // epilogue: divide by l (rows aligned with oacc), store bf16 into ob [s][n*d]
#pragma unroll
  for (int r = 0; r < 16; r++) {
    const float li = 1.f / lacc[r];
    const size_t row = (size_t)(s0 + wq + (r & 3) + 8 * (r >> 2) + 4 * hl);
#pragma unroll
    for (int dj = 0; dj < 4; dj++)
      ob[row * DIMD + hh * HD + dj * 32 + l31] = (bf16_t)(oacc[dj][r] * li);
  }
}

// ---------------- launch ----------------
extern "C" void kernel_launch(void* const* d_in, const int* in_sizes, int n_in,
                              void* d_out, int out_size, void* d_ws, size_t ws_size,
                              hipStream_t stream) {
  (void)in_sizes; (void)n_in; (void)out_size;
  const float* x     = (const float*)d_in[0];
  const float* freqs = (const float*)d_in[1];
  const float* Wq    = (const float*)d_in[2];
  const float* bq    = (const float*)d_in[3];
  const float* Wk    = (const float*)d_in[4];
  const float* bk    = (const float*)d_in[5];
  const float* Wv    = (const float*)d_in[6];
  const float* bv    = (const float*)d_in[7];
  const float* Wo    = (const float*)d_in[8];
  const float* bo    = (const float*)d_in[9];
  const float* gq    = (const float*)d_in[10];
  const float* gk    = (const float*)d_in[11];

  // workspace carve (bytes); [0, 37748736) holds xb+Wqkvb during gemm1,
  // reused afterwards for pk / pvt.
  char* w = (char*)d_ws;
  bf16_t* xb    = (bf16_t*)(w);                 // x bf16:        12,582,912 B
  bf16_t* Wqkvb = (bf16_t*)(w + 12582912);      // Wq|Wk|Wv bf16: 25,165,824 B
  bf16_t* Wob   = (bf16_t*)(w + 37748736);      // Wo bf16:        8,388,608 B
  bf16_t* qkvb  = (bf16_t*)(w + 46137344);      // qkv bf16:      37,748,736 B
  bf16_t* obuf  = (bf16_t*)(w + 83886080);      // attn out bf16: 12,582,912 B
  float*  bqkv  = (float*) (w + 96468992);      // stacked bias:      24,576 B
  bf16_t* pk    = (bf16_t*)(w);                 // K packed [16][3072][128]: 12,582,912 B
  bf16_t* pvt   = (bf16_t*)(w + 12582912);      // V^T [16][128][3072]:      12,582,912 B
  if (ws_size < (size_t)96493568) return;

  // converts + bias pack (one launch)
  cvt_all<<<11288, 256, 0, stream>>>(x, Wq, Wk, Wv, Wo, bq, bk, bv, xb, Wqkvb, Wob, bqkv);

  // qkv = x @ [Wq;Wk;Wv]^T + bias   (3072 x 6144 x 2048)
  gemm_nt<true><<<dim3(48, 24), 256, 0, stream>>>(xb, Wqkvb, bqkv, qkvb, SEQ, QKVN, DIMD);
  // fused RMS+RoPE (q in-place, k -> pk) and V transpose (-> pvt), one launch
  prep<<<3840, 256, 0, stream>>>(qkvb, pk, pvt, gq, gk, freqs);
  // attention (fixed-m, 32x32 MFMA, in-register P, XCD head-clustering) -> obuf
  flash_attn<<<dim3(512), 192, 0, stream>>>(qkvb, pk, pvt, obuf);
  // out = obuf @ Wo^T + bo  (3072 x 2048 x 2048), fp32 out
  gemm_nt<false><<<dim3(16, 24), 256, 0, stream>>>(obuf, Wob, bo, (float*)d_out, SEQ, DIMD, DIMD);
}

// Round 13
// 394.330 us; speedup vs baseline: 1.2310x; 1.0260x over previous
//
#include <hip/hip_runtime.h>
#include <stdint.h>
#include <stddef.h>

typedef __bf16 bf16_t;
typedef __bf16 bf16x8 __attribute__((ext_vector_type(8)));
typedef __bf16 bf16x4 __attribute__((ext_vector_type(4)));
typedef __bf16 bf16x2 __attribute__((ext_vector_type(2)));
typedef float  f32x4  __attribute__((ext_vector_type(4)));
typedef float  f32x16 __attribute__((ext_vector_type(16)));

#define SEQ   3072
#define DIMD  2048
#define NH    16
#define HD    128
#define QKVN  6144

__device__ __forceinline__ void async16(const bf16_t* g, bf16_t* l) {
  __builtin_amdgcn_global_load_lds((const __attribute__((address_space(1))) uint32_t*)g,
                                   (__attribute__((address_space(3))) uint32_t*)l, 16, 0, 0);
}

// ---------------- fused converts + bias pack (one launch) ----------------
__global__ __launch_bounds__(256) void cvt_all(const float* __restrict__ x,
                                               const float* __restrict__ Wq,
                                               const float* __restrict__ Wk,
                                               const float* __restrict__ Wv,
                                               const float* __restrict__ Wo,
                                               const float* __restrict__ bq,
                                               const float* __restrict__ bk,
                                               const float* __restrict__ bv,
                                               bf16_t* __restrict__ xb,
                                               bf16_t* __restrict__ Wqkvb,
                                               bf16_t* __restrict__ Wob,
                                               float* __restrict__ bqkv) {
  const int b = blockIdx.x;
  const float* src; bf16_t* dst; int off;
  if (b < 3072)       { src = x;  dst = xb;              off = b; }
  else if (b < 5120)  { src = Wq; dst = Wqkvb;           off = b - 3072; }
  else if (b < 7168)  { src = Wk; dst = Wqkvb + 4194304; off = b - 5120; }
  else if (b < 9216)  { src = Wv; dst = Wqkvb + 8388608; off = b - 7168; }
  else if (b < 11264) { src = Wo; dst = Wob;             off = b - 9216; }
  else {  // bias pack: 24 blocks cover 6144
    int t = (b - 11264) * 256 + threadIdx.x;
    float v;
    if (t < 2048)      v = bq[t];
    else if (t < 4096) v = bk[t - 2048];
    else               v = bv[t - 4096];
    bqkv[t] = v;
    return;
  }
  const int idx = (off * 256 + threadIdx.x) * 8;
  const float4 a = *(const float4*)(src + idx);
  const float4 c = *(const float4*)(src + idx + 4);
  bf16x8 o;
  o[0] = (bf16_t)a.x; o[1] = (bf16_t)a.y; o[2] = (bf16_t)a.z; o[3] = (bf16_t)a.w;
  o[4] = (bf16_t)c.x; o[5] = (bf16_t)c.y; o[6] = (bf16_t)c.z; o[7] = (bf16_t)c.w;
  *(bf16x8*)(dst + idx) = o;
}

// ---------------- GEMM: C[M,N] = A[M,K] * B[N,K]^T + bias (128^2 tile) ----------------
// T1 XCD clustering (flat grid): XCD x owns PN contiguous N-panels; within-chunk
// ordering is n-fastest so co-resident blocks share B-panels in the XCD's L2
// (B-panel re-reads 24x -> L2 hits instead of L3/HBM streams).
template<bool OUT_BF16>
__global__ __launch_bounds__(256, 3) void gemm_nt(const bf16_t* __restrict__ A,
                                                  const bf16_t* __restrict__ B,
                                                  const float* __restrict__ bias,
                                                  void* __restrict__ Cout,
                                                  int M, int N, int K, int PN) {
  __shared__ __align__(16) bf16_t As[128 * 64];
  __shared__ __align__(16) bf16_t Bs[128 * 64];
  const int t = threadIdx.x;
  const int lane = t & 63, wave = t >> 6;
  const int quad = lane >> 4, l15 = lane & 15;
  const int wy = wave >> 1, wx = wave & 1;
  const int f = blockIdx.x;
  const int xcd = f & 7, local = f >> 3;           // grid is a multiple of 8
  const int mblk = local / PN, nblk = xcd * PN + local % PN;
  const size_t bm = (size_t)mblk * 128, bn = (size_t)nblk * 128;
  const bf16_t* Ab = A + bm * K;
  const bf16_t* Bb = B + bn * K;
  f32x4 acc[4][4] = {};
  int srow[4], scol[4];
#pragma unroll
  for (int r = 0; r < 4; r++) {
    int L = r * 256 + t;
    int row = L >> 3, cp = L & 7;
    srow[r] = row;
    scol[r] = (cp ^ (row & 7)) * 8;
  }
  for (int k0 = 0; k0 < K; k0 += 64) {
    __syncthreads();
#pragma unroll
    for (int r = 0; r < 4; r++)
      async16(Ab + (size_t)srow[r] * K + k0 + scol[r], &As[(r * 256 + t) * 8]);
#pragma unroll
    for (int r = 0; r < 4; r++)
      async16(Bb + (size_t)srow[r] * K + k0 + scol[r], &Bs[(r * 256 + t) * 8]);
    __syncthreads();
#pragma unroll
    for (int ks = 0; ks < 2; ks++) {
      bf16x8 af[4], bfv[4];
#pragma unroll
      for (int i = 0; i < 4; i++) {
        int row = wy * 64 + i * 16 + l15;
        af[i] = *(const bf16x8*)&As[row * 64 + (((ks * 4 + quad) ^ (row & 7)) * 8)];
      }
#pragma unroll
      for (int j = 0; j < 4; j++) {
        int row = wx * 64 + j * 16 + l15;
        bfv[j] = *(const bf16x8*)&Bs[row * 64 + (((ks * 4 + quad) ^ (row & 7)) * 8)];
      }
#pragma unroll
      for (int i = 0; i < 4; i++)
#pragma unroll
        for (int j = 0; j < 4; j++)
          acc[i][j] = __builtin_amdgcn_mfma_f32_16x16x32_bf16(af[i], bfv[j], acc[i][j], 0, 0, 0);
    }
  }
#pragma unroll
  for (int i = 0; i < 4; i++) {
#pragma unroll
    for (int j = 0; j < 4; j++) {
      size_t row = bm + wy * 64 + i * 16 + quad * 4;
      size_t col = bn + wx * 64 + j * 16 + l15;
      float bb = bias[col];
#pragma unroll
      for (int r = 0; r < 4; r++) {
        float v = acc[i][j][r] + bb;
        if (OUT_BF16) ((bf16_t*)Cout)[(row + r) * N + col] = (bf16_t)v;
        else          ((float*)Cout)[(row + r) * N + col] = v;
      }
    }
  }
}

// ---------------- fused prep: RMS+RoPE (blocks 0..3071) | V transpose (blocks 3072..3839) ----------------
// q is pre-scaled by (1/sqrt(128))*log2(e) = 0.12751745 so flash uses exp2 directly.
__global__ __launch_bounds__(256) void prep(bf16_t* __restrict__ qkv,
                                            bf16_t* __restrict__ pk,
                                            bf16_t* __restrict__ pvt,
                                            const float* __restrict__ gq,
                                            const float* __restrict__ gk,
                                            const float* __restrict__ freqs) {
  __shared__ bf16_t tile[128][65];
  __shared__ float red[2][4];
  const int t = threadIdx.x;
  if (blockIdx.x < 3072) {
    // ---- RMS + RoPE ----
    const int s = blockIdx.x;
    bf16_t* row = qkv + (size_t)s * QKVN;
    bf16x8 qv = *(const bf16x8*)&row[t * 8];
    bf16x8 kv = *(const bf16x8*)&row[2048 + t * 8];
    float qf[8], kf[8];
    float qs = 0.f, ks2 = 0.f;
#pragma unroll
    for (int i = 0; i < 8; i++) {
      qf[i] = (float)qv[i]; qs  += qf[i] * qf[i];
      kf[i] = (float)kv[i]; ks2 += kf[i] * kf[i];
    }
#pragma unroll
    for (int m = 1; m < 64; m <<= 1) {
      qs  += __shfl_xor(qs, m);
      ks2 += __shfl_xor(ks2, m);
    }
    const int wave = t >> 6, lane = t & 63;
    if (lane == 0) { red[0][wave] = qs; red[1][wave] = ks2; }
    __syncthreads();
    qs  = red[0][0] + red[0][1] + red[0][2] + red[0][3];
    ks2 = red[1][0] + red[1][1] + red[1][2] + red[1][3];
    const float qsc = rsqrtf(qs  / 2048.f + 1e-6f) * 0.12751745f; // fold attn scale*log2e
    const float ksc = rsqrtf(ks2 / 2048.f + 1e-6f);
    const int sf = s / 384, rem = s - sf * 384;
    const int sh = rem / 24, sw = rem - sh * 24;
    bf16x8 qo, ko;
#pragma unroll
    for (int u = 0; u < 4; u++) {
      const int col = t * 8 + 2 * u;
      const int i = (col >> 1) & 63;                         // pair index within head (c=64)
      const int frow = (i < 22) ? sf : ((i < 43) ? sh : sw); // cf=22, ch=cw=21
      const float ang = freqs[frow * 64 + i];
      float sn, cs;
      __sincosf(ang, &sn, &cs);
      float te = qf[2 * u]     * qsc * gq[col];
      float to = qf[2 * u + 1] * qsc * gq[col + 1];
      qo[2 * u]     = (bf16_t)(te * cs - to * sn);
      qo[2 * u + 1] = (bf16_t)(te * sn + to * cs);
      te = kf[2 * u]     * ksc * gk[col];
      to = kf[2 * u + 1] * ksc * gk[col + 1];
      ko[2 * u]     = (bf16_t)(te * cs - to * sn);
      ko[2 * u + 1] = (bf16_t)(te * sn + to * cs);
    }
    *(bf16x8*)&row[t * 8] = qo;
    // packed K: pk[h][s][d], h = t>>4, d = (t&15)*8
    *(bf16x8*)&pk[((size_t)(t >> 4) * SEQ + s) * HD + (t & 15) * 8] = ko;
  } else {
    // ---- V transpose: pvt[h][d][s] ----
    const int idx = blockIdx.x - 3072;
    const int h = idx / 48;
    const int s0 = (idx - h * 48) * 64;
#pragma unroll
    for (int r = 0; r < 4; r++) {
      int L = r * 256 + t, s = L >> 4, cp = L & 15;
      bf16x8 v = *(const bf16x8*)&qkv[(size_t)(s0 + s) * QKVN + 4096 + h * HD + cp * 8];
#pragma unroll
      for (int i = 0; i < 8; i++) tile[cp * 8 + i][s] = v[i];
    }
    __syncthreads();
#pragma unroll
    for (int r = 0; r < 4; r++) {
      int L = r * 256 + t, d = L >> 3, c = L & 7;
      bf16x8 o;
#pragma unroll
      for (int i = 0; i < 8; i++) o[i] = tile[d][c * 8 + i];
      *(bf16x8*)&pvt[((size_t)h * HD + d) * SEQ + s0 + c * 8] = o;
    }
  }
}

// ---------------- Flash attention (R6 internals + T1 XCD head-clustering) ----------------
// 32x32x16 MFMA, in-register P, fixed-m. Grid 512 x 192thr, 2 blocks/CU.
// Swizzle wg=(f&7)*64+(f>>3): each XCD owns 2 heads -> K+V (3MB) L2-resident
// (R12 measured: FETCH 104.5 -> 18.5 MB).
#define STAGE_KV(BUF, KV1) do {                                              \
    _Pragma("unroll")                                                        \
    for (int r = 0; r < 5; r++) {                                            \
      int L = r * 192 + t;                                                   \
      async16(pkh + (size_t)(KV1) * HD + koff[r], &Ks[BUF][L * 8]);          \
      async16(pvh + (KV1) + voff[r], &Vt[BUF][L * 8]);                       \
    }                                                                        \
    if (t < 64) {                                                            \
      int L = 5 * 192 + t;                                                   \
      async16(pkh + (size_t)(KV1) * HD + koff[5], &Ks[BUF][L * 8]);          \
      async16(pvh + (KV1) + voff[5], &Vt[BUF][L * 8]);                       \
    }                                                                        \
  } while (0)

__global__ __launch_bounds__(192, 2) void flash_attn(const bf16_t* __restrict__ qkv,
                                                     const bf16_t* __restrict__ pk,
                                                     const bf16_t* __restrict__ pvt,
                                                     bf16_t* __restrict__ ob) {
  __shared__ __align__(16) bf16_t Ks[2][64 * 128];  // [kv][d], 16 chunks/row, xor-swizzled
  __shared__ __align__(16) bf16_t Vt[2][128 * 64];  // [d][kv], 8 chunks/row, xor-swizzled
  const int f = blockIdx.x;
  const int wg = (f & 7) * 64 + (f >> 3);   // XCD x owns wg in [x*64, x*64+63] = 2 heads
  const int hh = wg >> 5, qt = wg & 31;
  const int s0 = qt * 96;
  const int t = threadIdx.x, wave = t >> 6, lane = t & 63;
  const int l31 = lane & 31, hl = lane >> 5;
  const int wq = wave * 32;
  const bf16_t* pkh = pk  + (size_t)hh * (SEQ * HD);
  const bf16_t* pvh = pvt + (size_t)hh * (HD * SEQ);
  int koff[6], voff[6];
#pragma unroll
  for (int r = 0; r < 6; r++) {
    int L = r * 192 + t;
    int krow = L >> 4, kc = (L & 15) ^ (krow & 7);
    koff[r] = krow * HD + kc * 8;
    int vd = L >> 3, vc = (L & 7) ^ (vd & 7);
    voff[r] = vd * SEQ + vc * 8;
  }
  // Q fragments (B-operand): lane holds Q[q=l31][d = ks*16 + hl*8 + j]
  bf16x8 qfr[8];
#pragma unroll
  for (int ks = 0; ks < 8; ks++)
    qfr[ks] = *(const bf16x8*)&qkv[(size_t)(s0 + wq + l31) * QKVN + hh * HD + ks * 16 + hl * 8];
  bf16x8 vones;
#pragma unroll
  for (int i = 0; i < 8; i++) vones[i] = (bf16_t)1.0f;
  f32x16 oacc[4] = {};  // O[q(per-reg)][d = dj*32 + l31]
  f32x16 lacc = {};     // row-sum of P, same q-per-reg layout
  STAGE_KV(0, 0);
  for (int kt = 0; kt < SEQ / 64; kt++) {
    const int cur = kt & 1;
    __syncthreads();  // tile kt landed; all waves done reading buf cur^1
    if (kt + 1 < SEQ / 64) STAGE_KV(cur ^ 1, (kt + 1) * 64);
    // S^T = K * Q^T: st0 = kv 0..31, st1 = kv 32..63; col = q = l31,
    // row(reg r) = (r&3) + 8*(r>>2) + 4*hl. Log2 domain (Q pre-scaled).
    f32x16 st0 = {}, st1 = {};
    __builtin_amdgcn_s_setprio(1);
#pragma unroll
    for (int ks = 0; ks < 8; ks++) {
      const int r1 = 32 + l31;
      bf16x8 k0 = *(const bf16x8*)&Ks[cur][l31 * 128 + (((ks * 2 + hl) ^ (l31 & 7)) * 8)];
      bf16x8 k1 = *(const bf16x8*)&Ks[cur][r1 * 128 + (((ks * 2 + hl) ^ (r1 & 7)) * 8)];
      st0 = __builtin_amdgcn_mfma_f32_32x32x16_bf16(k0, qfr[ks], st0, 0, 0, 0);
      st1 = __builtin_amdgcn_mfma_f32_32x32x16_bf16(k1, qfr[ks], st1, 0, 0, 0);
    }
    __builtin_amdgcn_s_setprio(0);
    // P = exp2(st), fixed m=0 (|st| <~ 8 in log2 domain; validated R3/R4/R6 absmax)
    uint32_t c0[8], c1[8];
#pragma unroll
    for (int m = 0; m < 8; m++) {
      bf16x2 w0, w1;
      w0[0] = (bf16_t)__builtin_amdgcn_exp2f(st0[2 * m]);
      w0[1] = (bf16_t)__builtin_amdgcn_exp2f(st0[2 * m + 1]);
      w1[0] = (bf16_t)__builtin_amdgcn_exp2f(st1[2 * m]);
      w1[1] = (bf16_t)__builtin_amdgcn_exp2f(st1[2 * m + 1]);
      c0[m] = __builtin_bit_cast(uint32_t, w0);
      c1[m] = __builtin_bit_cast(uint32_t, w1);
    }
    // Build PV A-fragments: afrS holds P[q=l31][kv = S*16 + hl*8 + j].
    union U8 { uint32_t u[4]; bf16x8 v; } afr0, afr1, afr2, afr3;
#define BUILD_AFR(DST, CB, B) do {                                           \
      uint32_t sA = hl ? CB[(B) + 0] : CB[(B) + 2];                          \
      uint32_t sB = hl ? CB[(B) + 1] : CB[(B) + 3];                          \
      uint32_t rA = (uint32_t)__shfl_xor((int)sA, 32);                       \
      uint32_t rB = (uint32_t)__shfl_xor((int)sB, 32);                       \
      DST.u[0] = hl ? rA : CB[(B) + 0];                                      \
      DST.u[1] = hl ? rB : CB[(B) + 1];                                      \
      DST.u[2] = hl ? CB[(B) + 2] : rA;                                      \
      DST.u[3] = hl ? CB[(B) + 3] : rB;                                      \
    } while (0)
    BUILD_AFR(afr0, c0, 0);
    BUILD_AFR(afr1, c0, 4);
    BUILD_AFR(afr2, c1, 0);
    BUILD_AFR(afr3, c1, 4);
#undef BUILD_AFR
    // O += P * V ; l += P * 1 (ones-column trick)
    __builtin_amdgcn_s_setprio(1);
#define PV_STEP(AFR, S) do {                                                            \
      lacc = __builtin_amdgcn_mfma_f32_32x32x16_bf16(AFR.v, vones, lacc, 0, 0, 0);      \
      _Pragma("unroll")                                                                 \
      for (int dj = 0; dj < 4; dj++) {                                                  \
        const int row = dj * 32 + l31;                                                  \
        bf16x8 vf = *(const bf16x8*)&Vt[cur][row * 64 + ((((S) * 2 + hl) ^ (row & 7)) * 8)]; \
        oacc[dj] = __builtin_amdgcn_mfma_f32_32x32x16_bf16(AFR.v, vf, oacc[dj], 0, 0, 0);    \
      }                                                                                 \
    } while (0)
    PV_STEP(afr0, 0);
    PV_STEP(afr1, 1);
    PV_STEP(afr2, 2);
    PV_STEP(afr3, 3);
#undef PV_STEP
    __builtin_amdgcn_s_setprio(0);
  }
  // epilogue: divide by l (rows aligned with oacc), store bf16 into ob [s][n*d]
#pragma unroll
  for (int r = 0; r < 16; r++) {
    const float li = 1.f / lacc[r];
    const size_t row = (size_t)(s0 + wq + (r & 3) + 8 * (r >> 2) + 4 * hl);
#pragma unroll
    for (int dj = 0; dj < 4; dj++)
      ob[row * DIMD + hh * HD + dj * 32 + l31] = (bf16_t)(oacc[dj][r] * li);
  }
}

// ---------------- launch ----------------
extern "C" void kernel_launch(void* const* d_in, const int* in_sizes, int n_in,
                              void* d_out, int out_size, void* d_ws, size_t ws_size,
                              hipStream_t stream) {
  (void)in_sizes; (void)n_in; (void)out_size;
  const float* x     = (const float*)d_in[0];
  const float* freqs = (const float*)d_in[1];
  const float* Wq    = (const float*)d_in[2];
  const float* bq    = (const float*)d_in[3];
  const float* Wk    = (const float*)d_in[4];
  const float* bk    = (const float*)d_in[5];
  const float* Wv    = (const float*)d_in[6];
  const float* bv    = (const float*)d_in[7];
  const float* Wo    = (const float*)d_in[8];
  const float* bo    = (const float*)d_in[9];
  const float* gq    = (const float*)d_in[10];
  const float* gk    = (const float*)d_in[11];

  // workspace carve (bytes); [0, 37748736) holds xb+Wqkvb during gemm1,
  // reused afterwards for pk / pvt.
  char* w = (char*)d_ws;
  bf16_t* xb    = (bf16_t*)(w);                 // x bf16:        12,582,912 B
  bf16_t* Wqkvb = (bf16_t*)(w + 12582912);      // Wq|Wk|Wv bf16: 25,165,824 B
  bf16_t* Wob   = (bf16_t*)(w + 37748736);      // Wo bf16:        8,388,608 B
  bf16_t* qkvb  = (bf16_t*)(w + 46137344);      // qkv bf16:      37,748,736 B
  bf16_t* obuf  = (bf16_t*)(w + 83886080);      // attn out bf16: 12,582,912 B
  float*  bqkv  = (float*) (w + 96468992);      // stacked bias:      24,576 B
  bf16_t* pk    = (bf16_t*)(w);                 // K packed [16][3072][128]: 12,582,912 B
  bf16_t* pvt   = (bf16_t*)(w + 12582912);      // V^T [16][128][3072]:      12,582,912 B
  if (ws_size < (size_t)96493568) return;

  // converts + bias pack (one launch)
  cvt_all<<<11288, 256, 0, stream>>>(x, Wq, Wk, Wv, Wo, bq, bk, bv, xb, Wqkvb, Wob, bqkv);

  // qkv = x @ [Wq;Wk;Wv]^T + bias  (3072 x 6144 x 2048); XCD-clustered: 6 N-panels/XCD
  gemm_nt<true><<<dim3(1152), 256, 0, stream>>>(xb, Wqkvb, bqkv, qkvb, SEQ, QKVN, DIMD, 6);
  // fused RMS+RoPE (q in-place, k -> pk) and V transpose (-> pvt), one launch
  prep<<<3840, 256, 0, stream>>>(qkvb, pk, pvt, gq, gk, freqs);
  // attention (fixed-m, 32x32 MFMA, in-register P, XCD head-clustering) -> obuf
  flash_attn<<<dim3(512), 192, 0, stream>>>(qkvb, pk, pvt, obuf);
  // out = obuf @ Wo^T + bo  (3072 x 2048 x 2048); XCD-clustered: 2 N-panels/XCD
  gemm_nt<false><<<dim3(384), 256, 0, stream>>>(obuf, Wob, bo, (float*)d_out, SEQ, DIMD, DIMD, 2);
}